// Round 23
// baseline (107.333 us; speedup 1.0000x reference)
//
#include <hip/hip_runtime.h>
#include <hip/hip_bf16.h>

typedef __attribute__((ext_vector_type(8))) short short8;
typedef __attribute__((ext_vector_type(4))) float float4v;
typedef __attribute__((ext_vector_type(16))) float f32x16;
typedef __attribute__((ext_vector_type(4))) unsigned uint4v;

#define AS1(p) ((const __attribute__((address_space(1))) void*)(p))
#define AS3(p) ((__attribute__((address_space(3))) void*)(p))

#define NSPLIT 8

__device__ __forceinline__ ushort f2bf(float f) {
    union { float f; unsigned u; } v; v.f = f;
    unsigned u = v.u;
    unsigned r = (u + 0x7fffu + ((u >> 16) & 1u)) >> 16;
    return (ushort)r;
}
__device__ __forceinline__ float bf2f(ushort u) {
    union { unsigned u; float f; } v; v.u = ((unsigned)u) << 16;
    return v.f;
}

// ---------------- fused transpose+cast of both weights (one launch) ----------------
__global__ void transpose_cast2(const float* __restrict__ wqkv, ushort* __restrict__ wqkvT,
                                const float* __restrict__ wout, ushort* __restrict__ woutT) {
    int idx = blockIdx.x * blockDim.x + threadIdx.x;
    if (idx < 1024 * 384) {
        int r = idx / 384, c = idx - r * 384;
        wqkvT[(size_t)c * 1024 + r] = f2bf(wqkv[idx]);
    } else {
        int i2 = idx - 1024 * 384;
        if (i2 < 128 * 1024) {
            int r = i2 >> 10, c = i2 & 1023;
            woutT[(size_t)c * 128 + r] = f2bf(wout[i2]);
        }
    }
}

// ======================= tiled GEMM helpers =======================
__device__ __forceinline__ void stage128x64(const ushort* gbase, int ld, ushort* lds, int tid) {
    const int wavebase = tid & 192;
#pragma unroll
    for (int j = 0; j < 4; ++j) {
        int idx = j * 256 + tid;
        int row = idx >> 3;
        int slot = idx & 7;
        int s = slot ^ (row & 7);
        const ushort* g = gbase + (size_t)row * ld + s * 8;
        int ldsoff = (j * 256 + wavebase) * 16;
        __builtin_amdgcn_global_load_lds(AS1(g), AS3((char*)lds + ldsoff), 16, 0, 0);
    }
}

__device__ __forceinline__ void stage64x64(const ushort* gbase, int ld, ushort* lds, int tid) {
    const int wavebase = tid & 192;
#pragma unroll
    for (int j = 0; j < 2; ++j) {
        int idx = j * 256 + tid;
        int row = idx >> 3;
        int slot = idx & 7;
        int s = slot ^ (row & 7);
        const ushort* g = gbase + (size_t)row * ld + s * 8;
        int ldsoff = (j * 256 + wavebase) * 16;
        __builtin_amdgcn_global_load_lds(AS1(g), AS3((char*)lds + ldsoff), 16, 0, 0);
    }
}

// BM=64 BN=128 compute: wave (wr,wc) owns 32x64
__device__ __forceinline__ void compute64x128(const ushort* As, const ushort* Bs,
                                              int wr, int wc, int row16, int grp,
                                              float4v acc[2][4]) {
    const char* Ab = (const char*)As;
    const char* Bb = (const char*)Bs;
#pragma unroll
    for (int kk = 0; kk < 2; ++kk) {
        short8 a[2], b[4];
        const int sw = row16 & 7;
#pragma unroll
        for (int m = 0; m < 2; ++m)
            a[m] = *(const short8*)(Ab + (wr * 32 + m * 16 + row16) * 128 + (((kk * 4 + grp) ^ sw) << 4));
#pragma unroll
        for (int n = 0; n < 4; ++n)
            b[n] = *(const short8*)(Bb + (wc * 64 + n * 16 + row16) * 128 + (((kk * 4 + grp) ^ sw) << 4));
#pragma unroll
        for (int m = 0; m < 2; ++m)
#pragma unroll
            for (int n = 0; n < 4; ++n)
                acc[m][n] = __builtin_amdgcn_mfma_f32_16x16x32_bf16(a[m], b[n], acc[m][n], 0, 0, 0);
    }
}

// BM=64 BN=64 compute: wave (wr,wc) owns 32x32
__device__ __forceinline__ void compute64x64(const ushort* As, const ushort* Bs,
                                             int wr, int wc, int row16, int grp,
                                             float4v acc[2][2]) {
    const char* Ab = (const char*)As;
    const char* Bb = (const char*)Bs;
#pragma unroll
    for (int kk = 0; kk < 2; ++kk) {
        short8 a[2], b[2];
        const int sw = row16 & 7;
#pragma unroll
        for (int m = 0; m < 2; ++m)
            a[m] = *(const short8*)(Ab + (wr * 32 + m * 16 + row16) * 128 + (((kk * 4 + grp) ^ sw) << 4));
#pragma unroll
        for (int n = 0; n < 2; ++n)
            b[n] = *(const short8*)(Bb + (wc * 32 + n * 16 + row16) * 128 + (((kk * 4 + grp) ^ sw) << 4));
#pragma unroll
        for (int m = 0; m < 2; ++m)
#pragma unroll
            for (int n = 0; n < 2; ++n)
                acc[m][n] = __builtin_amdgcn_mfma_f32_16x16x32_bf16(a[m], b[n], acc[m][n], 0, 0, 0);
    }
}

// ---------------- GEMM1: qkv = bf16(x) @ w_qkv, fused cast, BM=64 BN=64 ----------------
// grid 1536: bx&7 = xcd, i = bx>>3, variant v = i%6 (by = v>>1, n-half = v&1),
// mt = (xcd*32 + i/6)*64 -> all 6 variants of one x panel on one XCD (L2-local).
__global__ __launch_bounds__(256) void gemm_qkv(const float* __restrict__ x,
                                                const ushort* __restrict__ wT,
                                                ushort* __restrict__ Qm,
                                                ushort* __restrict__ Km,
                                                ushort* __restrict__ Vt) {
    __shared__ ushort S[8192];             // As 64x64 (4096) + Bs 64x64 (4096); reused 64x72 transpose
    ushort* As = S;
    ushort* Bs = S + 4096;
    const int tid = threadIdx.x;
    const int lane = tid & 63, w = tid >> 6;
    const int row16 = lane & 15, grp = lane >> 4;
    const int wr = w >> 1, wc = w & 1;
    const int bx = blockIdx.x;             // 0..1535
    const int xcd = bx & 7;
    const int i = bx >> 3;                 // 0..191
    const int v = i % 6;
    const int by = v >> 1;                 // 0:Q 1:K 2:V
    const int nh = v & 1;                  // n-half
    const int mt = ((xcd << 5) + i / 6) << 6;   // bijective over 0..255 tiles
    const int n0 = by * 128 + nh * 64;

    float4v acc[2][2];
#pragma unroll
    for (int m = 0; m < 2; ++m)
#pragma unroll
        for (int n = 0; n < 2; ++n) acc[m][n] = (float4v){0.f, 0.f, 0.f, 0.f};

#define LOAD_A(KT)                                                         \
    _Pragma("unroll") for (int j = 0; j < 2; ++j) {                        \
        int idx = j * 256 + tid;                                           \
        int row = idx >> 3, slot = idx & 7;                                \
        const float* src = x + (size_t)(mt + row) * 1024 + (KT) + slot * 8;\
        va[j][0] = *(const float4*)(src);                                  \
        va[j][1] = *(const float4*)(src + 4);                              \
    }

    float4 va[2][2];
    LOAD_A(0);

    for (int kt = 0; kt < 1024; kt += 64) {
        // B: async LDS stage (pre-swizzled source, linear dest)
        stage64x64(wT + (size_t)n0 * 1024 + kt, 1024, Bs, tid);
        // A: cvt prefetched regs (v_cvt_pk_bf16_f32) -> swizzled ds_write
#pragma unroll
        for (int j = 0; j < 2; ++j) {
            int idx = j * 256 + tid;
            int row = idx >> 3, slot = idx & 7;
            unsigned h0, h1, h2, h3;
            asm("v_cvt_pk_bf16_f32 %0, %1, %2" : "=v"(h0) : "v"(va[j][0].x), "v"(va[j][0].y));
            asm("v_cvt_pk_bf16_f32 %0, %1, %2" : "=v"(h1) : "v"(va[j][0].z), "v"(va[j][0].w));
            asm("v_cvt_pk_bf16_f32 %0, %1, %2" : "=v"(h2) : "v"(va[j][1].x), "v"(va[j][1].y));
            asm("v_cvt_pk_bf16_f32 %0, %1, %2" : "=v"(h3) : "v"(va[j][1].z), "v"(va[j][1].w));
            union { uint4v u; short8 s; } hh;
            hh.u = (uint4v){h0, h1, h2, h3};
            *(short8*)((char*)As + row * 128 + ((slot ^ (row & 7)) << 4)) = hh.s;
        }
        __syncthreads();
        if (kt + 64 < 1024) LOAD_A(kt + 64);   // prefetch next A; latency hides under compute
        compute64x64(As, Bs, wr, wc, row16, grp, acc);
        __syncthreads();
    }
#undef LOAD_A

    if (by == 2) {
        // ---- V: transpose 64t x 64d tile in LDS, write Vt[b][d][t] coalesced ----
#pragma unroll
        for (int m = 0; m < 2; ++m)
#pragma unroll
            for (int i2 = 0; i2 < 4; ++i2) {
                int trow = wr * 32 + m * 16 + grp * 4 + i2;
#pragma unroll
                for (int n = 0; n < 2; ++n) {
                    int dl = wc * 32 + n * 16 + row16;
                    S[dl * 72 + trow] = f2bf(acc[m][n][i2]);
                }
            }
        __syncthreads();
        const int b = mt >> 12, tloc = mt & 4095;
#pragma unroll
        for (int j = 0; j < 2; ++j) {
            int chunk = j * 256 + tid;          // 0..511
            int dl = chunk >> 3, tc = chunk & 7;
            *(short8*)(Vt + ((size_t)(b * 128 + nh * 64 + dl)) * 4096 + tloc + tc * 8) =
                *(const short8*)(S + dl * 72 + tc * 8);
        }
        return;
    }

    const float oscale = (by == 0) ? (0.03125f * 1.44269504f) : 1.0f;
    ushort* dst = (by == 0) ? Qm : Km;
#pragma unroll
    for (int m = 0; m < 2; ++m)
#pragma unroll
        for (int i2 = 0; i2 < 4; ++i2) {
            int row = mt + wr * 32 + m * 16 + grp * 4 + i2;
#pragma unroll
            for (int n = 0; n < 2; ++n) {
                int coll = nh * 64 + wc * 32 + n * 16 + row16;
                dst[(size_t)row * 128 + coll] = f2bf(acc[m][n][i2] * oscale);
            }
        }
}

// ---------------- flash attention: swapped QK^T, in-register P, KVBLK=64 ----------------
__global__ __launch_bounds__(256, 2) void attn_split(const ushort* __restrict__ Qm,
                                                     const ushort* __restrict__ Km,
                                                     const ushort* __restrict__ Vt,
                                                     ushort* __restrict__ Opart,
                                                     float* __restrict__ Lpart) {
    __shared__ ushort Ks[2][64 * 128];   // [t][d], 16 chunks/row, swz (c&8)|((c&7)^(row&7))
    __shared__ ushort Vs[2][128 * 64];   // [d][t], 8 chunks/row, swz c^(row&7)

    const int tid = threadIdx.x;
    const int lane = tid & 63, w = tid >> 6;
    const int key31 = lane & 31;                       // A-row (key) / B-row (q,d)
    const int g = lane >> 5;                           // k-group

    const int bx = blockIdx.x;
    const int xcd = bx & 7;
    const int b = xcd >> 1;
    const int combo = ((bx >> 3) << 1) | (xcd & 1);    // 0..255
    const int qb = 31 - (combo >> 3);                  // heavy blocks first
    const int s = combo & 7;

    const int ext = 2 * qb + 2;                        // 64-key tiles in block extent
    const int t0 = (s * ext) >> 3;
    const int t1 = ((s + 1) * ext) >> 3;

    const int qtile32 = qb * 4 + w;
    const int qt0 = qtile32 * 32;
    const int qmax = qt0 + 31;
    const size_t pbase = ((size_t)b * 128 + qtile32) * NSPLIT + s;
    float* mlL = Lpart + pbase * 32;

    if (t0 >= t1) {                                    // block-uniform early out
        if (lane < 32) mlL[lane] = 0.f;
        return;
    }

    const int qrow = qt0 + key31;
    // Q pre-scaled by C^-0.5*log2(e); B-operand layout: row=lane&31, k=g*8+i
    const ushort* qbp = Qm + ((size_t)(b * 4096 + qrow)) * 128 + g * 8;
    short8 qf[8];
#pragma unroll
    for (int sl = 0; sl < 8; ++sl)
        qf[sl] = *reinterpret_cast<const short8*>(qbp + sl * 16);

    f32x16 o[4];
#pragma unroll
    for (int d4 = 0; d4 < 4; ++d4)
#pragma unroll
        for (int r = 0; r < 16; ++r) o[d4][r] = 0.f;
    float lrun = 0.f;

    const ushort* kbase = Km + (size_t)b * 4096 * 128;
    const ushort* vbase = Vt + (size_t)b * 128 * 4096;

// stage one 64-key tile: K 64x16 chunks + V 128x8 chunks = 8 gload_lds/thread
#define STAGE_KV(KVT, BUF)                                                                     \
    {                                                                                          \
        const ushort* kb_ = kbase + (size_t)(KVT) * 128;                                       \
        _Pragma("unroll") for (int j = 0; j < 4; ++j) {                                        \
            int idx = j * 256 + tid;                                                           \
            int row = idx >> 4, c = idx & 15;                                                  \
            int sc_ = (c & 8) | ((c & 7) ^ (row & 7));                                         \
            __builtin_amdgcn_global_load_lds(AS1(kb_ + (size_t)row * 128 + sc_ * 8),           \
                AS3((char*)&Ks[BUF][0] + (j * 256 + (tid & 192)) * 16), 16, 0, 0);             \
        }                                                                                      \
        const ushort* vb_ = vbase + (KVT);                                                     \
        _Pragma("unroll") for (int j = 0; j < 4; ++j) {                                        \
            int idx = j * 256 + tid;                                                           \
            int row = idx >> 3, c = idx & 7;                                                   \
            int sc_ = c ^ (row & 7);                                                           \
            __builtin_amdgcn_global_load_lds(AS1(vb_ + (size_t)row * 4096 + sc_ * 8),          \
                AS3((char*)&Vs[BUF][0] + (j * 256 + (tid & 192)) * 16), 16, 0, 0);             \
        }                                                                                      \
    }

    STAGE_KV(t0 * 64, 0);

    int cur = 0;
    for (int t = t0; t < t1; ++t) {
        const int kvt = t * 64;
        __builtin_amdgcn_s_barrier();                  // prev compute done reading cur^1
        if (t + 1 < t1) {
            STAGE_KV((t + 1) * 64, cur ^ 1);
            asm volatile("s_waitcnt vmcnt(8)" ::: "memory");  // tile t's 8 landed; t+1 in flight
        } else {
            asm volatile("s_waitcnt vmcnt(0)" ::: "memory");
        }
        __builtin_amdgcn_s_barrier();                  // buf cur readable by all waves

        if (kvt <= qmax) {
            // ---- swapped QK^T: two 32x32 outputs (keys 0..31, 32..63) ----
            const char* Kb = (const char*)&Ks[cur][0];
            f32x16 st0, st1;
#pragma unroll
            for (int r = 0; r < 16; ++r) { st0[r] = 0.f; st1[r] = 0.f; }
#pragma unroll
            for (int sl = 0; sl < 8; ++sl) {
                int c = sl * 2 + g;
                int sc_ = (c & 8) | ((c & 7) ^ (key31 & 7));
                short8 k0 = *(const short8*)(Kb + key31 * 256 + sc_ * 16);
                st0 = __builtin_amdgcn_mfma_f32_32x32x16_bf16(k0, qf[sl], st0, 0, 0, 0);
                short8 k1 = *(const short8*)(Kb + (32 + key31) * 256 + sc_ * 16);
                st1 = __builtin_amdgcn_mfma_f32_32x32x16_bf16(k1, qf[sl], st1, 0, 0, 0);
            }
            // ---- causal mask ----
            if (kvt + 63 > qt0) {
#pragma unroll
                for (int r = 0; r < 16; ++r) {
                    int key = kvt + (r & 3) + 8 * (r >> 2) + 4 * g;
                    if (key > qrow) st0[r] = -3e38f;
                    if (key + 32 > qrow) st1[r] = -3e38f;
                }
            }
            // ---- static-max softmax in-register ----
#pragma unroll
            for (int r = 0; r < 16; ++r) {
                float p0 = exp2f(st0[r]);
                float p1 = exp2f(st1[r]);
                st0[r] = p0; st1[r] = p1;
                lrun += p0 + p1;
            }
            // ---- PA fragments: 16 cvt_pk + 8 permlane32_swap (T12) ----
            unsigned pk0, pk1, pk2, pk3, pk4, pk5, pk6, pk7;
            unsigned qk0, qk1, qk2, qk3, qk4, qk5, qk6, qk7;
            asm("v_cvt_pk_bf16_f32 %0, %1, %2" : "=v"(pk0) : "v"(st0[0]),  "v"(st0[1]));
            asm("v_cvt_pk_bf16_f32 %0, %1, %2" : "=v"(pk1) : "v"(st0[2]),  "v"(st0[3]));
            asm("v_cvt_pk_bf16_f32 %0, %1, %2" : "=v"(pk2) : "v"(st0[4]),  "v"(st0[5]));
            asm("v_cvt_pk_bf16_f32 %0, %1, %2" : "=v"(pk3) : "v"(st0[6]),  "v"(st0[7]));
            asm("v_cvt_pk_bf16_f32 %0, %1, %2" : "=v"(pk4) : "v"(st0[8]),  "v"(st0[9]));
            asm("v_cvt_pk_bf16_f32 %0, %1, %2" : "=v"(pk5) : "v"(st0[10]), "v"(st0[11]));
            asm("v_cvt_pk_bf16_f32 %0, %1, %2" : "=v"(pk6) : "v"(st0[12]), "v"(st0[13]));
            asm("v_cvt_pk_bf16_f32 %0, %1, %2" : "=v"(pk7) : "v"(st0[14]), "v"(st0[15]));
            asm("v_cvt_pk_bf16_f32 %0, %1, %2" : "=v"(qk0) : "v"(st1[0]),  "v"(st1[1]));
            asm("v_cvt_pk_bf16_f32 %0, %1, %2" : "=v"(qk1) : "v"(st1[2]),  "v"(st1[3]));
            asm("v_cvt_pk_bf16_f32 %0, %1, %2" : "=v"(qk2) : "v"(st1[4]),  "v"(st1[5]));
            asm("v_cvt_pk_bf16_f32 %0, %1, %2" : "=v"(qk3) : "v"(st1[6]),  "v"(st1[7]));
            asm("v_cvt_pk_bf16_f32 %0, %1, %2" : "=v"(qk4) : "v"(st1[8]),  "v"(st1[9]));
            asm("v_cvt_pk_bf16_f32 %0, %1, %2" : "=v"(qk5) : "v"(st1[10]), "v"(st1[11]));
            asm("v_cvt_pk_bf16_f32 %0, %1, %2" : "=v"(qk6) : "v"(st1[12]), "v"(st1[13]));
            asm("v_cvt_pk_bf16_f32 %0, %1, %2" : "=v"(qk7) : "v"(st1[14]), "v"(st1[15]));
            asm volatile("v_permlane32_swap_b32 %0, %1" : "+v"(pk0), "+v"(pk2));
            asm volatile("v_permlane32_swap_b32 %0, %1" : "+v"(pk1), "+v"(pk3));
            asm volatile("v_permlane32_swap_b32 %0, %1" : "+v"(pk4), "+v"(pk6));
            asm volatile("v_permlane32_swap_b32 %0, %1" : "+v"(pk5), "+v"(pk7));
            asm volatile("v_permlane32_swap_b32 %0, %1" : "+v"(qk0), "+v"(qk2));
            asm volatile("v_permlane32_swap_b32 %0, %1" : "+v"(qk1), "+v"(qk3));
            asm volatile("v_permlane32_swap_b32 %0, %1" : "+v"(qk4), "+v"(qk6));
            asm volatile("v_permlane32_swap_b32 %0, %1" : "+v"(qk5), "+v"(qk7));
            union FW { uint4v u; short8 s; };
            FW f0; f0.u = (uint4v){pk0, pk1, pk2, pk3};
            FW f1; f1.u = (uint4v){pk4, pk5, pk6, pk7};
            FW f2; f2.u = (uint4v){qk0, qk1, qk2, qk3};
            FW f3; f3.u = (uint4v){qk4, qk5, qk6, qk7};
            short8 fa0 = f0.s;                         // keys kvt+0..15
            short8 fa1 = f1.s;                         // keys kvt+16..31
            short8 fa2 = f2.s;                         // keys kvt+32..47
            short8 fa3 = f3.s;                         // keys kvt+48..63
            // ---- PV: O[q][d] += P x V over 64 keys (4 k-slots) ----
            const char* Vb = (const char*)&Vs[cur][0];
#pragma unroll
            for (int d4 = 0; d4 < 4; ++d4) {
                int d = d4 * 32 + key31;
                int sw = d & 7;
                short8 v0 = *(const short8*)(Vb + d * 128 + ((0 * 2 + g) ^ sw) * 16);
                o[d4] = __builtin_amdgcn_mfma_f32_32x32x16_bf16(fa0, v0, o[d4], 0, 0, 0);
                short8 v1 = *(const short8*)(Vb + d * 128 + ((1 * 2 + g) ^ sw) * 16);
                o[d4] = __builtin_amdgcn_mfma_f32_32x32x16_bf16(fa1, v1, o[d4], 0, 0, 0);
                short8 v2 = *(const short8*)(Vb + d * 128 + ((2 * 2 + g) ^ sw) * 16);
                o[d4] = __builtin_amdgcn_mfma_f32_32x32x16_bf16(fa2, v2, o[d4], 0, 0, 0);
                short8 v3 = *(const short8*)(Vb + d * 128 + ((3 * 2 + g) ^ sw) * 16);
                o[d4] = __builtin_amdgcn_mfma_f32_32x32x16_bf16(fa3, v3, o[d4], 0, 0, 0);
            }
        }
        cur ^= 1;
    }
#undef STAGE_KV

    // ---- merge the two k-halves' row sums ----
    lrun += __shfl_xor(lrun, 32);
    // ---- write partial (unnormalized O bf16, denom l) ----
    // o layout: row q = (r&3)+8*(r>>2)+4g, col d = d4*32+key31
    ushort* ob = Opart + pbase * 32 * 128;
#pragma unroll
    for (int d4 = 0; d4 < 4; ++d4)
#pragma unroll
        for (int r = 0; r < 16; ++r) {
            int qr = (r & 3) + 8 * (r >> 2) + 4 * g;
            ob[(size_t)qr * 128 + d4 * 32 + key31] = f2bf(o[d4][r]);
        }
    if (lane < 32) mlL[lane] = lrun;
}

// ---------------- combine: plain sum over splits (static max), 2 rows/block ----------------
__global__ __launch_bounds__(256) void attn_combine(const ushort* __restrict__ Opart,
                                                    const float* __restrict__ Lpart,
                                                    ushort* __restrict__ AO) {
    const int row = blockIdx.x * 2 + (threadIdx.x >> 7);
    const int b = row >> 12, t = row & 4095;
    const int qtile = t >> 5, r = t & 31;
    const size_t sb = (((size_t)b * 128 + qtile) * NSPLIT);
    const int col = threadIdx.x & 127;
    float acc = 0.f, denom = 0.f;
#pragma unroll
    for (int s = 0; s < NSPLIT; ++s) {
        float l = Lpart[(sb + s) * 32 + r];
        if (l > 0.f) {
            denom += l;
            acc += bf2f(Opart[((sb + s) * 32 + r) * 128 + col]);
        }
    }
    AO[(size_t)row * 128 + col] = f2bf(acc / denom);
}

// ---------------- GEMM2: out = AO @ w_out + b_out, BM=64 ----------------
__global__ __launch_bounds__(256) void gemm_out(const ushort* __restrict__ AO,
                                                const ushort* __restrict__ wT,
                                                const float* __restrict__ bias,
                                                float* __restrict__ out) {
    __shared__ ushort As[64 * 64];
    __shared__ ushort Bs[128 * 64];
    const int tid = threadIdx.x;
    const int lane = tid & 63, w = tid >> 6;
    const int row16 = lane & 15, grp = lane >> 4;
    const int wr = w >> 1, wc = w & 1;
    const int mt = blockIdx.x * 64;
    const int n0 = blockIdx.y * 128;

    float4v acc[2][4];
#pragma unroll
    for (int m = 0; m < 2; ++m)
#pragma unroll
        for (int n = 0; n < 4; ++n) acc[m][n] = (float4v){0.f, 0.f, 0.f, 0.f};

#pragma unroll
    for (int kt = 0; kt < 128; kt += 64) {
        stage64x64(AO + (size_t)mt * 128 + kt, 128, As, tid);
        stage128x64(wT + (size_t)n0 * 128 + kt, 128, Bs, tid);
        __syncthreads();
        compute64x128(As, Bs, wr, wc, row16, grp, acc);
        __syncthreads();
    }

#pragma unroll
    for (int n = 0; n < 4; ++n) {
        int col = n0 + wc * 64 + n * 16 + row16;
        float bv = bias[col];
#pragma unroll
        for (int m = 0; m < 2; ++m)
#pragma unroll
            for (int i = 0; i < 4; ++i) {
                int row = mt + wr * 32 + m * 16 + grp * 4 + i;
                out[(size_t)row * 1024 + col] = acc[m][n][i] + bv;
            }
    }
}

extern "C" void kernel_launch(void* const* d_in, const int* in_sizes, int n_in,
                              void* d_out, int out_size, void* d_ws, size_t ws_size,
                              hipStream_t stream) {
    const float* x     = (const float*)d_in[0];   // [4,4096,1024]
    const float* w_qkv = (const float*)d_in[1];   // [1024,384]
    const float* w_out = (const float*)d_in[2];   // [128,1024]
    const float* b_out = (const float*)d_in[3];   // [1024]
    float* out = (float*)d_out;

    char* ws = (char*)d_ws;
    ushort* wqkvT = (ushort*)(ws + 33554432);      //    786,432 B
    ushort* woutT = (ushort*)(ws + 34340864);      //    262,144 B
    ushort* Qm    = (ushort*)(ws + 34603008);      //  4,194,304 B
    ushort* Km    = (ushort*)(ws + 38797312);      //  4,194,304 B
    ushort* Vt    = (ushort*)(ws + 42991616);      //  4,194,304 B
    ushort* AO    = (ushort*)(ws + 47185920);      //  4,194,304 B
    ushort* Opart = (ushort*)(ws);                 // 33,554,432 B (ws base)
    float* Lpart  = (float*)(ws + 51380224);       //    524,288 B

    // both weight transposes in one launch
    transpose_cast2<<<dim3(2048), dim3(256), 0, stream>>>(w_qkv, wqkvT, w_out, woutT);

    // QKV projection: fused cast, BM=64 BN=64, XCD-localized mapping (6 variants/tile)
    gemm_qkv<<<dim3(1536), dim3(256), 0, stream>>>(x, wqkvT, Qm, Km, Vt);

    // causal flash attention: swapped QK^T, in-register P, KVBLK=64, NSPLIT=8
    attn_split<<<dim3(1024), dim3(256), 0, stream>>>(Qm, Km, Vt, Opart, Lpart);
    attn_combine<<<dim3(8192), dim3(256), 0, stream>>>(Opart, Lpart, AO);

    // output projection + bias (tiled, BM=64)
    gemm_out<<<dim3(256, 8), dim3(256), 0, stream>>>(AO, woutT, b_out, out);
}

// Round 24
// 99.765 us; speedup vs baseline: 1.0759x; 1.0759x over previous
//
#include <hip/hip_runtime.h>
#include <hip/hip_bf16.h>

typedef __attribute__((ext_vector_type(8))) short short8;
typedef __attribute__((ext_vector_type(4))) float float4v;
typedef __attribute__((ext_vector_type(16))) float f32x16;
typedef __attribute__((ext_vector_type(4))) unsigned uint4v;

#define AS1(p) ((const __attribute__((address_space(1))) void*)(p))
#define AS3(p) ((__attribute__((address_space(3))) void*)(p))

#define NSPLIT 8

__device__ __forceinline__ ushort f2bf(float f) {
    union { float f; unsigned u; } v; v.f = f;
    unsigned u = v.u;
    unsigned r = (u + 0x7fffu + ((u >> 16) & 1u)) >> 16;
    return (ushort)r;
}
__device__ __forceinline__ float bf2f(ushort u) {
    union { unsigned u; float f; } v; v.u = ((unsigned)u) << 16;
    return v.f;
}

// ---------------- fused transpose+cast of both weights (one launch) ----------------
__global__ void transpose_cast2(const float* __restrict__ wqkv, ushort* __restrict__ wqkvT,
                                const float* __restrict__ wout, ushort* __restrict__ woutT) {
    int idx = blockIdx.x * blockDim.x + threadIdx.x;
    if (idx < 1024 * 384) {
        int r = idx / 384, c = idx - r * 384;
        wqkvT[(size_t)c * 1024 + r] = f2bf(wqkv[idx]);
    } else {
        int i2 = idx - 1024 * 384;
        if (i2 < 128 * 1024) {
            int r = i2 >> 10, c = i2 & 1023;
            woutT[(size_t)c * 128 + r] = f2bf(wout[i2]);
        }
    }
}

// ======================= tiled GEMM helpers =======================
__device__ __forceinline__ void stage128x64(const ushort* gbase, int ld, ushort* lds, int tid) {
    const int wavebase = tid & 192;
#pragma unroll
    for (int j = 0; j < 4; ++j) {
        int idx = j * 256 + tid;
        int row = idx >> 3;
        int slot = idx & 7;
        int s = slot ^ (row & 7);
        const ushort* g = gbase + (size_t)row * ld + s * 8;
        int ldsoff = (j * 256 + wavebase) * 16;
        __builtin_amdgcn_global_load_lds(AS1(g), AS3((char*)lds + ldsoff), 16, 0, 0);
    }
}

__device__ __forceinline__ void stage64x64(const ushort* gbase, int ld, ushort* lds, int tid) {
    const int wavebase = tid & 192;
#pragma unroll
    for (int j = 0; j < 2; ++j) {
        int idx = j * 256 + tid;
        int row = idx >> 3;
        int slot = idx & 7;
        int s = slot ^ (row & 7);
        const ushort* g = gbase + (size_t)row * ld + s * 8;
        int ldsoff = (j * 256 + wavebase) * 16;
        __builtin_amdgcn_global_load_lds(AS1(g), AS3((char*)lds + ldsoff), 16, 0, 0);
    }
}

// BM=64 compute: wave (wr,wc) owns 32x64; A 64x64, B 128x64
__device__ __forceinline__ void compute64x128(const ushort* As, const ushort* Bs,
                                              int wr, int wc, int row16, int grp,
                                              float4v acc[2][4]) {
    const char* Ab = (const char*)As;
    const char* Bb = (const char*)Bs;
#pragma unroll
    for (int kk = 0; kk < 2; ++kk) {
        short8 a[2], b[4];
        const int sw = row16 & 7;
#pragma unroll
        for (int m = 0; m < 2; ++m)
            a[m] = *(const short8*)(Ab + (wr * 32 + m * 16 + row16) * 128 + (((kk * 4 + grp) ^ sw) << 4));
#pragma unroll
        for (int n = 0; n < 4; ++n)
            b[n] = *(const short8*)(Bb + (wc * 64 + n * 16 + row16) * 128 + (((kk * 4 + grp) ^ sw) << 4));
#pragma unroll
        for (int m = 0; m < 2; ++m)
#pragma unroll
            for (int n = 0; n < 4; ++n)
                acc[m][n] = __builtin_amdgcn_mfma_f32_16x16x32_bf16(a[m], b[n], acc[m][n], 0, 0, 0);
    }
}

// ---------------- GEMM1: qkv = bf16(x) @ w_qkv, fused cast (cvt_pk), BM=64 ----------------
// XCD-localized grid: bx&7 = xcd, the 3 by-variants of one mt tile run on the
// SAME XCD consecutively -> x panel fetched into that L2 once (was 3 L3 passes).
// by=0 -> Q (pre-scaled), by=1 -> K, by=2 -> V transposed to Vt.
__global__ __launch_bounds__(256) void gemm_qkv(const float* __restrict__ x,
                                                const ushort* __restrict__ wT,
                                                ushort* __restrict__ Qm,
                                                ushort* __restrict__ Km,
                                                ushort* __restrict__ Vt) {
    __shared__ ushort S[12288];            // As 64x64 (4096) + Bs 128x64 (8192); reused 128x72 transpose
    ushort* As = S;
    ushort* Bs = S + 4096;
    const int tid = threadIdx.x;
    const int lane = tid & 63, w = tid >> 6;
    const int row16 = lane & 15, grp = lane >> 4;
    const int wr = w >> 1, wc = w & 1;
    const int bx = blockIdx.x;             // 0..767
    const int xcd = bx & 7;
    const int i = bx >> 3;                 // 0..95
    const int by = i % 3;
    const int mt = ((xcd << 5) + i / 3) << 6;   // (xcd*32 + i/3) * 64, bijective over 0..255
    const int n0 = by * 128;

    float4v acc[2][4];
#pragma unroll
    for (int m = 0; m < 2; ++m)
#pragma unroll
        for (int n = 0; n < 4; ++n) acc[m][n] = (float4v){0.f, 0.f, 0.f, 0.f};

#define LOAD_A(KT)                                                         \
    _Pragma("unroll") for (int j = 0; j < 2; ++j) {                        \
        int idx = j * 256 + tid;                                           \
        int row = idx >> 3, slot = idx & 7;                                \
        const float* src = x + (size_t)(mt + row) * 1024 + (KT) + slot * 8;\
        va[j][0] = *(const float4*)(src);                                  \
        va[j][1] = *(const float4*)(src + 4);                              \
    }

    float4 va[2][2];
    LOAD_A(0);

    for (int kt = 0; kt < 1024; kt += 64) {
        // B: async LDS stage (pre-swizzled source, linear dest)
        stage128x64(wT + (size_t)n0 * 1024 + kt, 1024, Bs, tid);
        // A: cvt prefetched regs (v_cvt_pk_bf16_f32) -> swizzled ds_write
#pragma unroll
        for (int j = 0; j < 2; ++j) {
            int idx = j * 256 + tid;
            int row = idx >> 3, slot = idx & 7;
            unsigned h0, h1, h2, h3;
            asm("v_cvt_pk_bf16_f32 %0, %1, %2" : "=v"(h0) : "v"(va[j][0].x), "v"(va[j][0].y));
            asm("v_cvt_pk_bf16_f32 %0, %1, %2" : "=v"(h1) : "v"(va[j][0].z), "v"(va[j][0].w));
            asm("v_cvt_pk_bf16_f32 %0, %1, %2" : "=v"(h2) : "v"(va[j][1].x), "v"(va[j][1].y));
            asm("v_cvt_pk_bf16_f32 %0, %1, %2" : "=v"(h3) : "v"(va[j][1].z), "v"(va[j][1].w));
            union { uint4v u; short8 s; } hh;
            hh.u = (uint4v){h0, h1, h2, h3};
            *(short8*)((char*)As + row * 128 + ((slot ^ (row & 7)) << 4)) = hh.s;
        }
        __syncthreads();
        if (kt + 64 < 1024) LOAD_A(kt + 64);   // prefetch next A; latency hides under compute
        compute64x128(As, Bs, wr, wc, row16, grp, acc);
        __syncthreads();
    }
#undef LOAD_A

    if (by == 2) {
        // ---- V: transpose 64t x 128d tile in LDS, write Vt[b][d][t] coalesced ----
#pragma unroll
        for (int m = 0; m < 2; ++m)
#pragma unroll
            for (int i2 = 0; i2 < 4; ++i2) {
                int trow = wr * 32 + m * 16 + grp * 4 + i2;
#pragma unroll
                for (int n = 0; n < 4; ++n) {
                    int d = wc * 64 + n * 16 + row16;
                    S[d * 72 + trow] = f2bf(acc[m][n][i2]);
                }
            }
        __syncthreads();
        const int b = mt >> 12, tloc = mt & 4095;
#pragma unroll
        for (int j = 0; j < 4; ++j) {
            int chunk = j * 256 + tid;          // 0..1023
            int d = chunk >> 3, tc = chunk & 7;
            *(short8*)(Vt + ((size_t)(b * 128 + d)) * 4096 + tloc + tc * 8) =
                *(const short8*)(S + d * 72 + tc * 8);
        }
        return;
    }

    const float oscale = (by == 0) ? (0.03125f * 1.44269504f) : 1.0f;
    ushort* dst = (by == 0) ? Qm : Km;
#pragma unroll
    for (int m = 0; m < 2; ++m)
#pragma unroll
        for (int i2 = 0; i2 < 4; ++i2) {
            int row = mt + wr * 32 + m * 16 + grp * 4 + i2;
#pragma unroll
            for (int n = 0; n < 4; ++n) {
                int coll = wc * 64 + n * 16 + row16;
                dst[(size_t)row * 128 + coll] = f2bf(acc[m][n][i2] * oscale);
            }
        }
}

// ---------------- flash attention: swapped QK^T, in-register P, KVBLK=64 ----------------
__global__ __launch_bounds__(256, 2) void attn_split(const ushort* __restrict__ Qm,
                                                     const ushort* __restrict__ Km,
                                                     const ushort* __restrict__ Vt,
                                                     ushort* __restrict__ Opart,
                                                     float* __restrict__ Lpart) {
    __shared__ ushort Ks[2][64 * 128];   // [t][d], 16 chunks/row, swz (c&8)|((c&7)^(row&7))
    __shared__ ushort Vs[2][128 * 64];   // [d][t], 8 chunks/row, swz c^(row&7)

    const int tid = threadIdx.x;
    const int lane = tid & 63, w = tid >> 6;
    const int key31 = lane & 31;                       // A-row (key) / B-row (q,d)
    const int g = lane >> 5;                           // k-group

    const int bx = blockIdx.x;
    const int xcd = bx & 7;
    const int b = xcd >> 1;
    const int combo = ((bx >> 3) << 1) | (xcd & 1);    // 0..255
    const int qb = 31 - (combo >> 3);                  // heavy blocks first
    const int s = combo & 7;

    const int ext = 2 * qb + 2;                        // 64-key tiles in block extent
    const int t0 = (s * ext) >> 3;
    const int t1 = ((s + 1) * ext) >> 3;

    const int qtile32 = qb * 4 + w;
    const int qt0 = qtile32 * 32;
    const int qmax = qt0 + 31;
    const size_t pbase = ((size_t)b * 128 + qtile32) * NSPLIT + s;
    float* mlL = Lpart + pbase * 32;

    if (t0 >= t1) {                                    // block-uniform early out
        if (lane < 32) mlL[lane] = 0.f;
        return;
    }

    const int qrow = qt0 + key31;
    // Q pre-scaled by C^-0.5*log2(e); B-operand layout: row=lane&31, k=g*8+i
    const ushort* qbp = Qm + ((size_t)(b * 4096 + qrow)) * 128 + g * 8;
    short8 qf[8];
#pragma unroll
    for (int sl = 0; sl < 8; ++sl)
        qf[sl] = *reinterpret_cast<const short8*>(qbp + sl * 16);

    f32x16 o[4];
#pragma unroll
    for (int d4 = 0; d4 < 4; ++d4)
#pragma unroll
        for (int r = 0; r < 16; ++r) o[d4][r] = 0.f;
    float lrun = 0.f;

    const ushort* kbase = Km + (size_t)b * 4096 * 128;
    const ushort* vbase = Vt + (size_t)b * 128 * 4096;

// stage one 64-key tile: K 64x16 chunks + V 128x8 chunks = 8 gload_lds/thread
#define STAGE_KV(KVT, BUF)                                                                     \
    {                                                                                          \
        const ushort* kb_ = kbase + (size_t)(KVT) * 128;                                       \
        _Pragma("unroll") for (int j = 0; j < 4; ++j) {                                        \
            int idx = j * 256 + tid;                                                           \
            int row = idx >> 4, c = idx & 15;                                                  \
            int sc_ = (c & 8) | ((c & 7) ^ (row & 7));                                         \
            __builtin_amdgcn_global_load_lds(AS1(kb_ + (size_t)row * 128 + sc_ * 8),           \
                AS3((char*)&Ks[BUF][0] + (j * 256 + (tid & 192)) * 16), 16, 0, 0);             \
        }                                                                                      \
        const ushort* vb_ = vbase + (KVT);                                                     \
        _Pragma("unroll") for (int j = 0; j < 4; ++j) {                                        \
            int idx = j * 256 + tid;                                                           \
            int row = idx >> 3, c = idx & 7;                                                   \
            int sc_ = c ^ (row & 7);                                                           \
            __builtin_amdgcn_global_load_lds(AS1(vb_ + (size_t)row * 4096 + sc_ * 8),          \
                AS3((char*)&Vs[BUF][0] + (j * 256 + (tid & 192)) * 16), 16, 0, 0);             \
        }                                                                                      \
    }

    STAGE_KV(t0 * 64, 0);

    int cur = 0;
    for (int t = t0; t < t1; ++t) {
        const int kvt = t * 64;
        __builtin_amdgcn_s_barrier();                  // prev compute done reading cur^1
        if (t + 1 < t1) {
            STAGE_KV((t + 1) * 64, cur ^ 1);
            asm volatile("s_waitcnt vmcnt(8)" ::: "memory");  // tile t's 8 landed; t+1 in flight
        } else {
            asm volatile("s_waitcnt vmcnt(0)" ::: "memory");
        }
        __builtin_amdgcn_s_barrier();                  // buf cur readable by all waves

        if (kvt <= qmax) {
            // ---- swapped QK^T: two 32x32 outputs (keys 0..31, 32..63) ----
            const char* Kb = (const char*)&Ks[cur][0];
            f32x16 st0, st1;
#pragma unroll
            for (int r = 0; r < 16; ++r) { st0[r] = 0.f; st1[r] = 0.f; }
#pragma unroll
            for (int sl = 0; sl < 8; ++sl) {
                int c = sl * 2 + g;
                int sc_ = (c & 8) | ((c & 7) ^ (key31 & 7));
                short8 k0 = *(const short8*)(Kb + key31 * 256 + sc_ * 16);
                st0 = __builtin_amdgcn_mfma_f32_32x32x16_bf16(k0, qf[sl], st0, 0, 0, 0);
                short8 k1 = *(const short8*)(Kb + (32 + key31) * 256 + sc_ * 16);
                st1 = __builtin_amdgcn_mfma_f32_32x32x16_bf16(k1, qf[sl], st1, 0, 0, 0);
            }
            // ---- causal mask ----
            if (kvt + 63 > qt0) {
#pragma unroll
                for (int r = 0; r < 16; ++r) {
                    int key = kvt + (r & 3) + 8 * (r >> 2) + 4 * g;
                    if (key > qrow) st0[r] = -3e38f;
                    if (key + 32 > qrow) st1[r] = -3e38f;
                }
            }
            // ---- static-max softmax in-register ----
#pragma unroll
            for (int r = 0; r < 16; ++r) {
                float p0 = exp2f(st0[r]);
                float p1 = exp2f(st1[r]);
                st0[r] = p0; st1[r] = p1;
                lrun += p0 + p1;
            }
            // ---- PA fragments: 16 cvt_pk + 8 permlane32_swap (T12) ----
            unsigned pk0, pk1, pk2, pk3, pk4, pk5, pk6, pk7;
            unsigned qk0, qk1, qk2, qk3, qk4, qk5, qk6, qk7;
            asm("v_cvt_pk_bf16_f32 %0, %1, %2" : "=v"(pk0) : "v"(st0[0]),  "v"(st0[1]));
            asm("v_cvt_pk_bf16_f32 %0, %1, %2" : "=v"(pk1) : "v"(st0[2]),  "v"(st0[3]));
            asm("v_cvt_pk_bf16_f32 %0, %1, %2" : "=v"(pk2) : "v"(st0[4]),  "v"(st0[5]));
            asm("v_cvt_pk_bf16_f32 %0, %1, %2" : "=v"(pk3) : "v"(st0[6]),  "v"(st0[7]));
            asm("v_cvt_pk_bf16_f32 %0, %1, %2" : "=v"(pk4) : "v"(st0[8]),  "v"(st0[9]));
            asm("v_cvt_pk_bf16_f32 %0, %1, %2" : "=v"(pk5) : "v"(st0[10]), "v"(st0[11]));
            asm("v_cvt_pk_bf16_f32 %0, %1, %2" : "=v"(pk6) : "v"(st0[12]), "v"(st0[13]));
            asm("v_cvt_pk_bf16_f32 %0, %1, %2" : "=v"(pk7) : "v"(st0[14]), "v"(st0[15]));
            asm("v_cvt_pk_bf16_f32 %0, %1, %2" : "=v"(qk0) : "v"(st1[0]),  "v"(st1[1]));
            asm("v_cvt_pk_bf16_f32 %0, %1, %2" : "=v"(qk1) : "v"(st1[2]),  "v"(st1[3]));
            asm("v_cvt_pk_bf16_f32 %0, %1, %2" : "=v"(qk2) : "v"(st1[4]),  "v"(st1[5]));
            asm("v_cvt_pk_bf16_f32 %0, %1, %2" : "=v"(qk3) : "v"(st1[6]),  "v"(st1[7]));
            asm("v_cvt_pk_bf16_f32 %0, %1, %2" : "=v"(qk4) : "v"(st1[8]),  "v"(st1[9]));
            asm("v_cvt_pk_bf16_f32 %0, %1, %2" : "=v"(qk5) : "v"(st1[10]), "v"(st1[11]));
            asm("v_cvt_pk_bf16_f32 %0, %1, %2" : "=v"(qk6) : "v"(st1[12]), "v"(st1[13]));
            asm("v_cvt_pk_bf16_f32 %0, %1, %2" : "=v"(qk7) : "v"(st1[14]), "v"(st1[15]));
            asm volatile("v_permlane32_swap_b32 %0, %1" : "+v"(pk0), "+v"(pk2));
            asm volatile("v_permlane32_swap_b32 %0, %1" : "+v"(pk1), "+v"(pk3));
            asm volatile("v_permlane32_swap_b32 %0, %1" : "+v"(pk4), "+v"(pk6));
            asm volatile("v_permlane32_swap_b32 %0, %1" : "+v"(pk5), "+v"(pk7));
            asm volatile("v_permlane32_swap_b32 %0, %1" : "+v"(qk0), "+v"(qk2));
            asm volatile("v_permlane32_swap_b32 %0, %1" : "+v"(qk1), "+v"(qk3));
            asm volatile("v_permlane32_swap_b32 %0, %1" : "+v"(qk4), "+v"(qk6));
            asm volatile("v_permlane32_swap_b32 %0, %1" : "+v"(qk5), "+v"(qk7));
            union FW { uint4v u; short8 s; };
            FW f0; f0.u = (uint4v){pk0, pk1, pk2, pk3};
            FW f1; f1.u = (uint4v){pk4, pk5, pk6, pk7};
            FW f2; f2.u = (uint4v){qk0, qk1, qk2, qk3};
            FW f3; f3.u = (uint4v){qk4, qk5, qk6, qk7};
            short8 fa0 = f0.s;                         // keys kvt+0..15
            short8 fa1 = f1.s;                         // keys kvt+16..31
            short8 fa2 = f2.s;                         // keys kvt+32..47
            short8 fa3 = f3.s;                         // keys kvt+48..63
            // ---- PV: O[q][d] += P x V over 64 keys (4 k-slots) ----
            const char* Vb = (const char*)&Vs[cur][0];
#pragma unroll
            for (int d4 = 0; d4 < 4; ++d4) {
                int d = d4 * 32 + key31;
                int sw = d & 7;
                short8 v0 = *(const short8*)(Vb + d * 128 + ((0 * 2 + g) ^ sw) * 16);
                o[d4] = __builtin_amdgcn_mfma_f32_32x32x16_bf16(fa0, v0, o[d4], 0, 0, 0);
                short8 v1 = *(const short8*)(Vb + d * 128 + ((1 * 2 + g) ^ sw) * 16);
                o[d4] = __builtin_amdgcn_mfma_f32_32x32x16_bf16(fa1, v1, o[d4], 0, 0, 0);
                short8 v2 = *(const short8*)(Vb + d * 128 + ((2 * 2 + g) ^ sw) * 16);
                o[d4] = __builtin_amdgcn_mfma_f32_32x32x16_bf16(fa2, v2, o[d4], 0, 0, 0);
                short8 v3 = *(const short8*)(Vb + d * 128 + ((3 * 2 + g) ^ sw) * 16);
                o[d4] = __builtin_amdgcn_mfma_f32_32x32x16_bf16(fa3, v3, o[d4], 0, 0, 0);
            }
        }
        cur ^= 1;
    }
#undef STAGE_KV

    // ---- merge the two k-halves' row sums ----
    lrun += __shfl_xor(lrun, 32);
    // ---- write partial (unnormalized O bf16, denom l) ----
    // o layout: row q = (r&3)+8*(r>>2)+4g, col d = d4*32+key31
    ushort* ob = Opart + pbase * 32 * 128;
#pragma unroll
    for (int d4 = 0; d4 < 4; ++d4)
#pragma unroll
        for (int r = 0; r < 16; ++r) {
            int qr = (r & 3) + 8 * (r >> 2) + 4 * g;
            ob[(size_t)qr * 128 + d4 * 32 + key31] = f2bf(o[d4][r]);
        }
    if (lane < 32) mlL[lane] = lrun;
}

// ---------------- combine: plain sum over splits (static max), 2 rows/block ----------------
__global__ __launch_bounds__(256) void attn_combine(const ushort* __restrict__ Opart,
                                                    const float* __restrict__ Lpart,
                                                    ushort* __restrict__ AO) {
    const int row = blockIdx.x * 2 + (threadIdx.x >> 7);
    const int b = row >> 12, t = row & 4095;
    const int qtile = t >> 5, r = t & 31;
    const size_t sb = (((size_t)b * 128 + qtile) * NSPLIT);
    const int col = threadIdx.x & 127;
    float acc = 0.f, denom = 0.f;
#pragma unroll
    for (int s = 0; s < NSPLIT; ++s) {
        float l = Lpart[(sb + s) * 32 + r];
        if (l > 0.f) {
            denom += l;
            acc += bf2f(Opart[((sb + s) * 32 + r) * 128 + col]);
        }
    }
    AO[(size_t)row * 128 + col] = f2bf(acc / denom);
}

// ---------------- GEMM2: out = AO @ w_out + b_out, BM=64 ----------------
__global__ __launch_bounds__(256) void gemm_out(const ushort* __restrict__ AO,
                                                const ushort* __restrict__ wT,
                                                const float* __restrict__ bias,
                                                float* __restrict__ out) {
    __shared__ ushort As[64 * 64];
    __shared__ ushort Bs[128 * 64];
    const int tid = threadIdx.x;
    const int lane = tid & 63, w = tid >> 6;
    const int row16 = lane & 15, grp = lane >> 4;
    const int wr = w >> 1, wc = w & 1;
    const int mt = blockIdx.x * 64;
    const int n0 = blockIdx.y * 128;

    float4v acc[2][4];
#pragma unroll
    for (int m = 0; m < 2; ++m)
#pragma unroll
        for (int n = 0; n < 4; ++n) acc[m][n] = (float4v){0.f, 0.f, 0.f, 0.f};

#pragma unroll
    for (int kt = 0; kt < 128; kt += 64) {
        stage64x64(AO + (size_t)mt * 128 + kt, 128, As, tid);
        stage128x64(wT + (size_t)n0 * 128 + kt, 128, Bs, tid);
        __syncthreads();
        compute64x128(As, Bs, wr, wc, row16, grp, acc);
        __syncthreads();
    }

#pragma unroll
    for (int n = 0; n < 4; ++n) {
        int col = n0 + wc * 64 + n * 16 + row16;
        float bv = bias[col];
#pragma unroll
        for (int m = 0; m < 2; ++m)
#pragma unroll
            for (int i = 0; i < 4; ++i) {
                int row = mt + wr * 32 + m * 16 + grp * 4 + i;
                out[(size_t)row * 1024 + col] = acc[m][n][i] + bv;
            }
    }
}

extern "C" void kernel_launch(void* const* d_in, const int* in_sizes, int n_in,
                              void* d_out, int out_size, void* d_ws, size_t ws_size,
                              hipStream_t stream) {
    const float* x     = (const float*)d_in[0];   // [4,4096,1024]
    const float* w_qkv = (const float*)d_in[1];   // [1024,384]
    const float* w_out = (const float*)d_in[2];   // [128,1024]
    const float* b_out = (const float*)d_in[3];   // [1024]
    float* out = (float*)d_out;

    char* ws = (char*)d_ws;
    ushort* wqkvT = (ushort*)(ws + 33554432);      //    786,432 B
    ushort* woutT = (ushort*)(ws + 34340864);      //    262,144 B
    ushort* Qm    = (ushort*)(ws + 34603008);      //  4,194,304 B
    ushort* Km    = (ushort*)(ws + 38797312);      //  4,194,304 B
    ushort* Vt    = (ushort*)(ws + 42991616);      //  4,194,304 B
    ushort* AO    = (ushort*)(ws + 47185920);      //  4,194,304 B
    ushort* Opart = (ushort*)(ws);                 // 33,554,432 B (ws base)
    float* Lpart  = (float*)(ws + 51380224);       //    524,288 B

    // both weight transposes in one launch
    transpose_cast2<<<dim3(2048), dim3(256), 0, stream>>>(w_qkv, wqkvT, w_out, woutT);

    // QKV projection: fused cast, BM=64, XCD-localized mt/by mapping
    gemm_qkv<<<dim3(768), dim3(256), 0, stream>>>(x, wqkvT, Qm, Km, Vt);

    // causal flash attention: swapped QK^T, in-register P, KVBLK=64, NSPLIT=8
    attn_split<<<dim3(1024), dim3(256), 0, stream>>>(Qm, Km, Vt, Opart, Lpart);
    attn_combine<<<dim3(8192), dim3(256), 0, stream>>>(Opart, Lpart, AO);

    // output projection + bias (tiled, BM=64)
    gemm_out<<<dim3(256, 8), dim3(256), 0, stream>>>(AO, woutT, b_out, out);
}

// Round 25
// 98.577 us; speedup vs baseline: 1.0888x; 1.0120x over previous
//
#include <hip/hip_runtime.h>
#include <hip/hip_bf16.h>

typedef __attribute__((ext_vector_type(8))) short short8;
typedef __attribute__((ext_vector_type(4))) float float4v;
typedef __attribute__((ext_vector_type(16))) float f32x16;
typedef __attribute__((ext_vector_type(4))) unsigned uint4v;

#define AS1(p) ((const __attribute__((address_space(1))) void*)(p))
#define AS3(p) ((__attribute__((address_space(3))) void*)(p))

#define NSPLIT 8

__device__ __forceinline__ ushort f2bf(float f) {
    union { float f; unsigned u; } v; v.f = f;
    unsigned u = v.u;
    unsigned r = (u + 0x7fffu + ((u >> 16) & 1u)) >> 16;
    return (ushort)r;
}
__device__ __forceinline__ float bf2f(ushort u) {
    union { unsigned u; float f; } v; v.u = ((unsigned)u) << 16;
    return v.f;
}

// ---------------- fused transpose+cast of both weights (one launch) ----------------
__global__ void transpose_cast2(const float* __restrict__ wqkv, ushort* __restrict__ wqkvT,
                                const float* __restrict__ wout, ushort* __restrict__ woutT) {
    int idx = blockIdx.x * blockDim.x + threadIdx.x;
    if (idx < 1024 * 384) {
        int r = idx / 384, c = idx - r * 384;
        wqkvT[(size_t)c * 1024 + r] = f2bf(wqkv[idx]);
    } else {
        int i2 = idx - 1024 * 384;
        if (i2 < 128 * 1024) {
            int r = i2 >> 10, c = i2 & 1023;
            woutT[(size_t)c * 128 + r] = f2bf(wout[i2]);
        }
    }
}

// ======================= tiled GEMM helpers =======================
__device__ __forceinline__ void stage128x64(const ushort* gbase, int ld, ushort* lds, int tid) {
    const int wavebase = tid & 192;
#pragma unroll
    for (int j = 0; j < 4; ++j) {
        int idx = j * 256 + tid;
        int row = idx >> 3;
        int slot = idx & 7;
        int s = slot ^ (row & 7);
        const ushort* g = gbase + (size_t)row * ld + s * 8;
        int ldsoff = (j * 256 + wavebase) * 16;
        __builtin_amdgcn_global_load_lds(AS1(g), AS3((char*)lds + ldsoff), 16, 0, 0);
    }
}

__device__ __forceinline__ void stage64x64(const ushort* gbase, int ld, ushort* lds, int tid) {
    const int wavebase = tid & 192;
#pragma unroll
    for (int j = 0; j < 2; ++j) {
        int idx = j * 256 + tid;
        int row = idx >> 3;
        int slot = idx & 7;
        int s = slot ^ (row & 7);
        const ushort* g = gbase + (size_t)row * ld + s * 8;
        int ldsoff = (j * 256 + wavebase) * 16;
        __builtin_amdgcn_global_load_lds(AS1(g), AS3((char*)lds + ldsoff), 16, 0, 0);
    }
}

// BM=64 compute: wave (wr,wc) owns 32x64; A 64x64, B 128x64
__device__ __forceinline__ void compute64x128(const ushort* As, const ushort* Bs,
                                              int wr, int wc, int row16, int grp,
                                              float4v acc[2][4]) {
    const char* Ab = (const char*)As;
    const char* Bb = (const char*)Bs;
#pragma unroll
    for (int kk = 0; kk < 2; ++kk) {
        short8 a[2], b[4];
        const int sw = row16 & 7;
#pragma unroll
        for (int m = 0; m < 2; ++m)
            a[m] = *(const short8*)(Ab + (wr * 32 + m * 16 + row16) * 128 + (((kk * 4 + grp) ^ sw) << 4));
#pragma unroll
        for (int n = 0; n < 4; ++n)
            b[n] = *(const short8*)(Bb + (wc * 64 + n * 16 + row16) * 128 + (((kk * 4 + grp) ^ sw) << 4));
#pragma unroll
        for (int m = 0; m < 2; ++m)
#pragma unroll
            for (int n = 0; n < 4; ++n)
                acc[m][n] = __builtin_amdgcn_mfma_f32_16x16x32_bf16(a[m], b[n], acc[m][n], 0, 0, 0);
    }
}

// ---------------- GEMM1: qkv = bf16(x) @ w_qkv, fused cast, BM=64, dbuf B ----------------
// XCD-localized grid (3 by-variants of one mt panel per XCD). B double-buffered:
// B(t+1)+A(t+1) issued before compute(t), latency hidden; only lgkmcnt drained
// at barrier2 (raw s_barrier pair). A(t)'s implicit reg-wait guarantees B(t)
// landed (B(t) was issued before A(t) last iteration).
__global__ __launch_bounds__(256) void gemm_qkv(const float* __restrict__ x,
                                                const ushort* __restrict__ wT,
                                                ushort* __restrict__ Qm,
                                                ushort* __restrict__ Km,
                                                ushort* __restrict__ Vt) {
    __shared__ ushort S[20480];            // As 64x64 (4096) + Bs dbuf 2 x 128x64 (8192 each)
    ushort* As = S;
    ushort* Bs[2] = { S + 4096, S + 12288 };
    const int tid = threadIdx.x;
    const int lane = tid & 63, w = tid >> 6;
    const int row16 = lane & 15, grp = lane >> 4;
    const int wr = w >> 1, wc = w & 1;
    const int bx = blockIdx.x;             // 0..767
    const int xcd = bx & 7;
    const int i = bx >> 3;                 // 0..95
    const int by = i % 3;
    const int mt = ((xcd << 5) + i / 3) << 6;   // (xcd*32 + i/3) * 64, bijective over 0..255
    const int n0 = by * 128;

    float4v acc[2][4];
#pragma unroll
    for (int m = 0; m < 2; ++m)
#pragma unroll
        for (int n = 0; n < 4; ++n) acc[m][n] = (float4v){0.f, 0.f, 0.f, 0.f};

#define LOAD_A(KT)                                                         \
    _Pragma("unroll") for (int j = 0; j < 2; ++j) {                        \
        int idx = j * 256 + tid;                                           \
        int row = idx >> 3, slot = idx & 7;                                \
        const float* src = x + (size_t)(mt + row) * 1024 + (KT) + slot * 8;\
        va[j][0] = *(const float4*)(src);                                  \
        va[j][1] = *(const float4*)(src + 4);                              \
    }

    float4 va[2][2];
    // prologue: B(0) then A(0)  (A after B so A's reg-wait implies B landed)
    stage128x64(wT + (size_t)n0 * 1024, 1024, Bs[0], tid);
    LOAD_A(0);

    int cur = 0;
    for (int kt = 0; kt < 1024; kt += 64) {
        __builtin_amdgcn_s_barrier();      // prev compute done reading As & Bs[cur^1]
        // A: cvt prefetched regs (forces wait on A(t) => B(t) also landed) -> swizzled ds_write
#pragma unroll
        for (int j = 0; j < 2; ++j) {
            int idx = j * 256 + tid;
            int row = idx >> 3, slot = idx & 7;
            unsigned h0, h1, h2, h3;
            asm("v_cvt_pk_bf16_f32 %0, %1, %2" : "=v"(h0) : "v"(va[j][0].x), "v"(va[j][0].y));
            asm("v_cvt_pk_bf16_f32 %0, %1, %2" : "=v"(h1) : "v"(va[j][0].z), "v"(va[j][0].w));
            asm("v_cvt_pk_bf16_f32 %0, %1, %2" : "=v"(h2) : "v"(va[j][1].x), "v"(va[j][1].y));
            asm("v_cvt_pk_bf16_f32 %0, %1, %2" : "=v"(h3) : "v"(va[j][1].z), "v"(va[j][1].w));
            union { uint4v u; short8 s; } hh;
            hh.u = (uint4v){h0, h1, h2, h3};
            *(short8*)((char*)As + row * 128 + ((slot ^ (row & 7)) << 4)) = hh.s;
        }
        // prefetch next tile: B first, then A (stay in flight across compute)
        if (kt + 64 < 1024) {
            stage128x64(wT + (size_t)n0 * 1024 + kt + 64, 1024, Bs[cur ^ 1], tid);
            LOAD_A(kt + 64);
        }
        asm volatile("s_waitcnt lgkmcnt(0)" ::: "memory");   // As writes visible
        __builtin_amdgcn_s_barrier();
        compute64x128(As, Bs[cur], wr, wc, row16, grp, acc);
        cur ^= 1;
    }
#undef LOAD_A

    if (by == 2) {
        // ---- V: transpose 64t x 128d tile in LDS, write Vt[b][d][t] coalesced ----
        __builtin_amdgcn_s_barrier();      // all waves done with As/Bs before S reuse
#pragma unroll
        for (int m = 0; m < 2; ++m)
#pragma unroll
            for (int i2 = 0; i2 < 4; ++i2) {
                int trow = wr * 32 + m * 16 + grp * 4 + i2;
#pragma unroll
                for (int n = 0; n < 4; ++n) {
                    int d = wc * 64 + n * 16 + row16;
                    S[d * 72 + trow] = f2bf(acc[m][n][i2]);
                }
            }
        __syncthreads();
        const int b = mt >> 12, tloc = mt & 4095;
#pragma unroll
        for (int j = 0; j < 4; ++j) {
            int chunk = j * 256 + tid;          // 0..1023
            int d = chunk >> 3, tc = chunk & 7;
            *(short8*)(Vt + ((size_t)(b * 128 + d)) * 4096 + tloc + tc * 8) =
                *(const short8*)(S + d * 72 + tc * 8);
        }
        return;
    }

    const float oscale = (by == 0) ? (0.03125f * 1.44269504f) : 1.0f;
    ushort* dst = (by == 0) ? Qm : Km;
#pragma unroll
    for (int m = 0; m < 2; ++m)
#pragma unroll
        for (int i2 = 0; i2 < 4; ++i2) {
            int row = mt + wr * 32 + m * 16 + grp * 4 + i2;
#pragma unroll
            for (int n = 0; n < 4; ++n) {
                int coll = wc * 64 + n * 16 + row16;
                dst[(size_t)row * 128 + coll] = f2bf(acc[m][n][i2] * oscale);
            }
        }
}

// ---------------- flash attention: swapped QK^T, in-register P, KVBLK=64 ----------------
__global__ __launch_bounds__(256, 2) void attn_split(const ushort* __restrict__ Qm,
                                                     const ushort* __restrict__ Km,
                                                     const ushort* __restrict__ Vt,
                                                     ushort* __restrict__ Opart,
                                                     float* __restrict__ Lpart) {
    __shared__ ushort Ks[2][64 * 128];   // [t][d], 16 chunks/row, swz (c&8)|((c&7)^(row&7))
    __shared__ ushort Vs[2][128 * 64];   // [d][t], 8 chunks/row, swz c^(row&7)

    const int tid = threadIdx.x;
    const int lane = tid & 63, w = tid >> 6;
    const int key31 = lane & 31;                       // A-row (key) / B-row (q,d)
    const int g = lane >> 5;                           // k-group

    const int bx = blockIdx.x;
    const int xcd = bx & 7;
    const int b = xcd >> 1;
    const int combo = ((bx >> 3) << 1) | (xcd & 1);    // 0..255
    const int qb = 31 - (combo >> 3);                  // heavy blocks first
    const int s = combo & 7;

    const int ext = 2 * qb + 2;                        // 64-key tiles in block extent
    const int t0 = (s * ext) >> 3;
    const int t1 = ((s + 1) * ext) >> 3;

    const int qtile32 = qb * 4 + w;
    const int qt0 = qtile32 * 32;
    const int qmax = qt0 + 31;
    const size_t pbase = ((size_t)b * 128 + qtile32) * NSPLIT + s;
    float* mlL = Lpart + pbase * 32;

    if (t0 >= t1) {                                    // block-uniform early out
        if (lane < 32) mlL[lane] = 0.f;
        return;
    }

    const int qrow = qt0 + key31;
    // Q pre-scaled by C^-0.5*log2(e); B-operand layout: row=lane&31, k=g*8+i
    const ushort* qbp = Qm + ((size_t)(b * 4096 + qrow)) * 128 + g * 8;
    short8 qf[8];
#pragma unroll
    for (int sl = 0; sl < 8; ++sl)
        qf[sl] = *reinterpret_cast<const short8*>(qbp + sl * 16);

    f32x16 o[4];
#pragma unroll
    for (int d4 = 0; d4 < 4; ++d4)
#pragma unroll
        for (int r = 0; r < 16; ++r) o[d4][r] = 0.f;
    float lrun = 0.f;

    const ushort* kbase = Km + (size_t)b * 4096 * 128;
    const ushort* vbase = Vt + (size_t)b * 128 * 4096;

// stage one 64-key tile: K 64x16 chunks + V 128x8 chunks = 8 gload_lds/thread
#define STAGE_KV(KVT, BUF)                                                                     \
    {                                                                                          \
        const ushort* kb_ = kbase + (size_t)(KVT) * 128;                                       \
        _Pragma("unroll") for (int j = 0; j < 4; ++j) {                                        \
            int idx = j * 256 + tid;                                                           \
            int row = idx >> 4, c = idx & 15;                                                  \
            int sc_ = (c & 8) | ((c & 7) ^ (row & 7));                                         \
            __builtin_amdgcn_global_load_lds(AS1(kb_ + (size_t)row * 128 + sc_ * 8),           \
                AS3((char*)&Ks[BUF][0] + (j * 256 + (tid & 192)) * 16), 16, 0, 0);             \
        }                                                                                      \
        const ushort* vb_ = vbase + (KVT);                                                     \
        _Pragma("unroll") for (int j = 0; j < 4; ++j) {                                        \
            int idx = j * 256 + tid;                                                           \
            int row = idx >> 3, c = idx & 7;                                                   \
            int sc_ = c ^ (row & 7);                                                           \
            __builtin_amdgcn_global_load_lds(AS1(vb_ + (size_t)row * 4096 + sc_ * 8),          \
                AS3((char*)&Vs[BUF][0] + (j * 256 + (tid & 192)) * 16), 16, 0, 0);             \
        }                                                                                      \
    }

    STAGE_KV(t0 * 64, 0);

    int cur = 0;
    for (int t = t0; t < t1; ++t) {
        const int kvt = t * 64;
        __builtin_amdgcn_s_barrier();                  // prev compute done reading cur^1
        if (t + 1 < t1) {
            STAGE_KV((t + 1) * 64, cur ^ 1);
            asm volatile("s_waitcnt vmcnt(8)" ::: "memory");  // tile t's 8 landed; t+1 in flight
        } else {
            asm volatile("s_waitcnt vmcnt(0)" ::: "memory");
        }
        __builtin_amdgcn_s_barrier();                  // buf cur readable by all waves

        if (kvt <= qmax) {
            // ---- swapped QK^T: two 32x32 outputs (keys 0..31, 32..63) ----
            const char* Kb = (const char*)&Ks[cur][0];
            f32x16 st0, st1;
#pragma unroll
            for (int r = 0; r < 16; ++r) { st0[r] = 0.f; st1[r] = 0.f; }
#pragma unroll
            for (int sl = 0; sl < 8; ++sl) {
                int c = sl * 2 + g;
                int sc_ = (c & 8) | ((c & 7) ^ (key31 & 7));
                short8 k0 = *(const short8*)(Kb + key31 * 256 + sc_ * 16);
                st0 = __builtin_amdgcn_mfma_f32_32x32x16_bf16(k0, qf[sl], st0, 0, 0, 0);
                short8 k1 = *(const short8*)(Kb + (32 + key31) * 256 + sc_ * 16);
                st1 = __builtin_amdgcn_mfma_f32_32x32x16_bf16(k1, qf[sl], st1, 0, 0, 0);
            }
            // ---- causal mask ----
            if (kvt + 63 > qt0) {
#pragma unroll
                for (int r = 0; r < 16; ++r) {
                    int key = kvt + (r & 3) + 8 * (r >> 2) + 4 * g;
                    if (key > qrow) st0[r] = -3e38f;
                    if (key + 32 > qrow) st1[r] = -3e38f;
                }
            }
            // ---- static-max softmax in-register ----
#pragma unroll
            for (int r = 0; r < 16; ++r) {
                float p0 = exp2f(st0[r]);
                float p1 = exp2f(st1[r]);
                st0[r] = p0; st1[r] = p1;
                lrun += p0 + p1;
            }
            // ---- PA fragments: 16 cvt_pk + 8 permlane32_swap (T12) ----
            unsigned pk0, pk1, pk2, pk3, pk4, pk5, pk6, pk7;
            unsigned qk0, qk1, qk2, qk3, qk4, qk5, qk6, qk7;
            asm("v_cvt_pk_bf16_f32 %0, %1, %2" : "=v"(pk0) : "v"(st0[0]),  "v"(st0[1]));
            asm("v_cvt_pk_bf16_f32 %0, %1, %2" : "=v"(pk1) : "v"(st0[2]),  "v"(st0[3]));
            asm("v_cvt_pk_bf16_f32 %0, %1, %2" : "=v"(pk2) : "v"(st0[4]),  "v"(st0[5]));
            asm("v_cvt_pk_bf16_f32 %0, %1, %2" : "=v"(pk3) : "v"(st0[6]),  "v"(st0[7]));
            asm("v_cvt_pk_bf16_f32 %0, %1, %2" : "=v"(pk4) : "v"(st0[8]),  "v"(st0[9]));
            asm("v_cvt_pk_bf16_f32 %0, %1, %2" : "=v"(pk5) : "v"(st0[10]), "v"(st0[11]));
            asm("v_cvt_pk_bf16_f32 %0, %1, %2" : "=v"(pk6) : "v"(st0[12]), "v"(st0[13]));
            asm("v_cvt_pk_bf16_f32 %0, %1, %2" : "=v"(pk7) : "v"(st0[14]), "v"(st0[15]));
            asm("v_cvt_pk_bf16_f32 %0, %1, %2" : "=v"(qk0) : "v"(st1[0]),  "v"(st1[1]));
            asm("v_cvt_pk_bf16_f32 %0, %1, %2" : "=v"(qk1) : "v"(st1[2]),  "v"(st1[3]));
            asm("v_cvt_pk_bf16_f32 %0, %1, %2" : "=v"(qk2) : "v"(st1[4]),  "v"(st1[5]));
            asm("v_cvt_pk_bf16_f32 %0, %1, %2" : "=v"(qk3) : "v"(st1[6]),  "v"(st1[7]));
            asm("v_cvt_pk_bf16_f32 %0, %1, %2" : "=v"(qk4) : "v"(st1[8]),  "v"(st1[9]));
            asm("v_cvt_pk_bf16_f32 %0, %1, %2" : "=v"(qk5) : "v"(st1[10]), "v"(st1[11]));
            asm("v_cvt_pk_bf16_f32 %0, %1, %2" : "=v"(qk6) : "v"(st1[12]), "v"(st1[13]));
            asm("v_cvt_pk_bf16_f32 %0, %1, %2" : "=v"(qk7) : "v"(st1[14]), "v"(st1[15]));
            asm volatile("v_permlane32_swap_b32 %0, %1" : "+v"(pk0), "+v"(pk2));
            asm volatile("v_permlane32_swap_b32 %0, %1" : "+v"(pk1), "+v"(pk3));
            asm volatile("v_permlane32_swap_b32 %0, %1" : "+v"(pk4), "+v"(pk6));
            asm volatile("v_permlane32_swap_b32 %0, %1" : "+v"(pk5), "+v"(pk7));
            asm volatile("v_permlane32_swap_b32 %0, %1" : "+v"(qk0), "+v"(qk2));
            asm volatile("v_permlane32_swap_b32 %0, %1" : "+v"(qk1), "+v"(qk3));
            asm volatile("v_permlane32_swap_b32 %0, %1" : "+v"(qk4), "+v"(qk6));
            asm volatile("v_permlane32_swap_b32 %0, %1" : "+v"(qk5), "+v"(qk7));
            union FW { uint4v u; short8 s; };
            FW f0; f0.u = (uint4v){pk0, pk1, pk2, pk3};
            FW f1; f1.u = (uint4v){pk4, pk5, pk6, pk7};
            FW f2; f2.u = (uint4v){qk0, qk1, qk2, qk3};
            FW f3; f3.u = (uint4v){qk4, qk5, qk6, qk7};
            short8 fa0 = f0.s;                         // keys kvt+0..15
            short8 fa1 = f1.s;                         // keys kvt+16..31
            short8 fa2 = f2.s;                         // keys kvt+32..47
            short8 fa3 = f3.s;                         // keys kvt+48..63
            // ---- PV: O[q][d] += P x V over 64 keys (4 k-slots) ----
            const char* Vb = (const char*)&Vs[cur][0];
#pragma unroll
            for (int d4 = 0; d4 < 4; ++d4) {
                int d = d4 * 32 + key31;
                int sw = d & 7;
                short8 v0 = *(const short8*)(Vb + d * 128 + ((0 * 2 + g) ^ sw) * 16);
                o[d4] = __builtin_amdgcn_mfma_f32_32x32x16_bf16(fa0, v0, o[d4], 0, 0, 0);
                short8 v1 = *(const short8*)(Vb + d * 128 + ((1 * 2 + g) ^ sw) * 16);
                o[d4] = __builtin_amdgcn_mfma_f32_32x32x16_bf16(fa1, v1, o[d4], 0, 0, 0);
                short8 v2 = *(const short8*)(Vb + d * 128 + ((2 * 2 + g) ^ sw) * 16);
                o[d4] = __builtin_amdgcn_mfma_f32_32x32x16_bf16(fa2, v2, o[d4], 0, 0, 0);
                short8 v3 = *(const short8*)(Vb + d * 128 + ((3 * 2 + g) ^ sw) * 16);
                o[d4] = __builtin_amdgcn_mfma_f32_32x32x16_bf16(fa3, v3, o[d4], 0, 0, 0);
            }
        }
        cur ^= 1;
    }
#undef STAGE_KV

    // ---- merge the two k-halves' row sums ----
    lrun += __shfl_xor(lrun, 32);
    // ---- write partial (unnormalized O bf16, denom l) ----
    // o layout: row q = (r&3)+8*(r>>2)+4g, col d = d4*32+key31
    ushort* ob = Opart + pbase * 32 * 128;
#pragma unroll
    for (int d4 = 0; d4 < 4; ++d4)
#pragma unroll
        for (int r = 0; r < 16; ++r) {
            int qr = (r & 3) + 8 * (r >> 2) + 4 * g;
            ob[(size_t)qr * 128 + d4 * 32 + key31] = f2bf(o[d4][r]);
        }
    if (lane < 32) mlL[lane] = lrun;
}

// ---------------- combine: plain sum over splits (static max), 2 rows/block ----------------
__global__ __launch_bounds__(256) void attn_combine(const ushort* __restrict__ Opart,
                                                    const float* __restrict__ Lpart,
                                                    ushort* __restrict__ AO) {
    const int row = blockIdx.x * 2 + (threadIdx.x >> 7);
    const int b = row >> 12, t = row & 4095;
    const int qtile = t >> 5, r = t & 31;
    const size_t sb = (((size_t)b * 128 + qtile) * NSPLIT);
    const int col = threadIdx.x & 127;
    float acc = 0.f, denom = 0.f;
#pragma unroll
    for (int s = 0; s < NSPLIT; ++s) {
        float l = Lpart[(sb + s) * 32 + r];
        if (l > 0.f) {
            denom += l;
            acc += bf2f(Opart[((sb + s) * 32 + r) * 128 + col]);
        }
    }
    AO[(size_t)row * 128 + col] = f2bf(acc / denom);
}

// ---------------- GEMM2: out = AO @ w_out + b_out, BM=64 ----------------
__global__ __launch_bounds__(256) void gemm_out(const ushort* __restrict__ AO,
                                                const ushort* __restrict__ wT,
                                                const float* __restrict__ bias,
                                                float* __restrict__ out) {
    __shared__ ushort As[64 * 64];
    __shared__ ushort Bs[128 * 64];
    const int tid = threadIdx.x;
    const int lane = tid & 63, w = tid >> 6;
    const int row16 = lane & 15, grp = lane >> 4;
    const int wr = w >> 1, wc = w & 1;
    const int mt = blockIdx.x * 64;
    const int n0 = blockIdx.y * 128;

    float4v acc[2][4];
#pragma unroll
    for (int m = 0; m < 2; ++m)
#pragma unroll
        for (int n = 0; n < 4; ++n) acc[m][n] = (float4v){0.f, 0.f, 0.f, 0.f};

#pragma unroll
    for (int kt = 0; kt < 128; kt += 64) {
        stage64x64(AO + (size_t)mt * 128 + kt, 128, As, tid);
        stage128x64(wT + (size_t)n0 * 128 + kt, 128, Bs, tid);
        __syncthreads();
        compute64x128(As, Bs, wr, wc, row16, grp, acc);
        __syncthreads();
    }

#pragma unroll
    for (int n = 0; n < 4; ++n) {
        int col = n0 + wc * 64 + n * 16 + row16;
        float bv = bias[col];
#pragma unroll
        for (int m = 0; m < 2; ++m)
#pragma unroll
            for (int i = 0; i < 4; ++i) {
                int row = mt + wr * 32 + m * 16 + grp * 4 + i;
                out[(size_t)row * 1024 + col] = acc[m][n][i] + bv;
            }
    }
}

extern "C" void kernel_launch(void* const* d_in, const int* in_sizes, int n_in,
                              void* d_out, int out_size, void* d_ws, size_t ws_size,
                              hipStream_t stream) {
    const float* x     = (const float*)d_in[0];   // [4,4096,1024]
    const float* w_qkv = (const float*)d_in[1];   // [1024,384]
    const float* w_out = (const float*)d_in[2];   // [128,1024]
    const float* b_out = (const float*)d_in[3];   // [1024]
    float* out = (float*)d_out;

    char* ws = (char*)d_ws;
    ushort* wqkvT = (ushort*)(ws + 33554432);      //    786,432 B
    ushort* woutT = (ushort*)(ws + 34340864);      //    262,144 B
    ushort* Qm    = (ushort*)(ws + 34603008);      //  4,194,304 B
    ushort* Km    = (ushort*)(ws + 38797312);      //  4,194,304 B
    ushort* Vt    = (ushort*)(ws + 42991616);      //  4,194,304 B
    ushort* AO    = (ushort*)(ws + 47185920);      //  4,194,304 B
    ushort* Opart = (ushort*)(ws);                 // 33,554,432 B (ws base)
    float* Lpart  = (float*)(ws + 51380224);       //    524,288 B

    // both weight transposes in one launch
    transpose_cast2<<<dim3(2048), dim3(256), 0, stream>>>(w_qkv, wqkvT, w_out, woutT);

    // QKV projection: fused cast, BM=64, XCD-localized mapping, dbuf B
    gemm_qkv<<<dim3(768), dim3(256), 0, stream>>>(x, wqkvT, Qm, Km, Vt);

    // causal flash attention: swapped QK^T, in-register P, KVBLK=64, NSPLIT=8
    attn_split<<<dim3(1024), dim3(256), 0, stream>>>(Qm, Km, Vt, Opart, Lpart);
    attn_combine<<<dim3(8192), dim3(256), 0, stream>>>(Opart, Lpart, AO);

    // output projection + bias (tiled, BM=64)
    gemm_out<<<dim3(256, 8), dim3(256), 0, stream>>>(AO, woutT, b_out, out);
}

// Round 27
// 98.330 us; speedup vs baseline: 1.0916x; 1.0025x over previous
//
#include <hip/hip_runtime.h>
#include <hip/hip_bf16.h>

typedef __attribute__((ext_vector_type(8))) short short8;
typedef __attribute__((ext_vector_type(4))) float float4v;
typedef __attribute__((ext_vector_type(16))) float f32x16;
typedef __attribute__((ext_vector_type(4))) unsigned uint4v;

#define AS1(p) ((const __attribute__((address_space(1))) void*)(p))
#define AS3(p) ((__attribute__((address_space(3))) void*)(p))

#define NSPLIT 8

__device__ __forceinline__ ushort f2bf(float f) {
    union { float f; unsigned u; } v; v.f = f;
    unsigned u = v.u;
    unsigned r = (u + 0x7fffu + ((u >> 16) & 1u)) >> 16;
    return (ushort)r;
}
__device__ __forceinline__ float bf2f(ushort u) {
    union { unsigned u; float f; } v; v.u = ((unsigned)u) << 16;
    return v.f;
}

// ---------------- fused transpose+cast of both weights (one launch) ----------------
__global__ void transpose_cast2(const float* __restrict__ wqkv, ushort* __restrict__ wqkvT,
                                const float* __restrict__ wout, ushort* __restrict__ woutT) {
    int idx = blockIdx.x * blockDim.x + threadIdx.x;
    if (idx < 1024 * 384) {
        int r = idx / 384, c = idx - r * 384;
        wqkvT[(size_t)c * 1024 + r] = f2bf(wqkv[idx]);
    } else {
        int i2 = idx - 1024 * 384;
        if (i2 < 128 * 1024) {
            int r = i2 >> 10, c = i2 & 1023;
            woutT[(size_t)c * 128 + r] = f2bf(wout[i2]);
        }
    }
}

// ======================= tiled GEMM helpers =======================
__device__ __forceinline__ void stage128x64(const ushort* gbase, int ld, ushort* lds, int tid) {
    const int wavebase = tid & 192;
#pragma unroll
    for (int j = 0; j < 4; ++j) {
        int idx = j * 256 + tid;
        int row = idx >> 3;
        int slot = idx & 7;
        int s = slot ^ (row & 7);
        const ushort* g = gbase + (size_t)row * ld + s * 8;
        int ldsoff = (j * 256 + wavebase) * 16;
        __builtin_amdgcn_global_load_lds(AS1(g), AS3((char*)lds + ldsoff), 16, 0, 0);
    }
}

__device__ __forceinline__ void stage64x64(const ushort* gbase, int ld, ushort* lds, int tid) {
    const int wavebase = tid & 192;
#pragma unroll
    for (int j = 0; j < 2; ++j) {
        int idx = j * 256 + tid;
        int row = idx >> 3;
        int slot = idx & 7;
        int s = slot ^ (row & 7);
        const ushort* g = gbase + (size_t)row * ld + s * 8;
        int ldsoff = (j * 256 + wavebase) * 16;
        __builtin_amdgcn_global_load_lds(AS1(g), AS3((char*)lds + ldsoff), 16, 0, 0);
    }
}

// BM=64 compute: wave (wr,wc) owns 32x64; A 64x64, B 128x64
__device__ __forceinline__ void compute64x128(const ushort* As, const ushort* Bs,
                                              int wr, int wc, int row16, int grp,
                                              float4v acc[2][4]) {
    const char* Ab = (const char*)As;
    const char* Bb = (const char*)Bs;
#pragma unroll
    for (int kk = 0; kk < 2; ++kk) {
        short8 a[2], b[4];
        const int sw = row16 & 7;
#pragma unroll
        for (int m = 0; m < 2; ++m)
            a[m] = *(const short8*)(Ab + (wr * 32 + m * 16 + row16) * 128 + (((kk * 4 + grp) ^ sw) << 4));
#pragma unroll
        for (int n = 0; n < 4; ++n)
            b[n] = *(const short8*)(Bb + (wc * 64 + n * 16 + row16) * 128 + (((kk * 4 + grp) ^ sw) << 4));
#pragma unroll
        for (int m = 0; m < 2; ++m)
#pragma unroll
            for (int n = 0; n < 4; ++n)
                acc[m][n] = __builtin_amdgcn_mfma_f32_16x16x32_bf16(a[m], b[n], acc[m][n], 0, 0, 0);
    }
}

// ---------------- GEMM1: qkv = bf16(x) @ w_qkv, fused cast, BM=64, dbuf B ----------------
// XCD-localized grid (3 by-variants of one mt panel per XCD). B double-buffered:
// B(t+1)+A(t+1) issued before compute(t), latency hidden; only lgkmcnt drained
// at barrier2 (raw s_barrier pair). A(t)'s implicit reg-wait guarantees B(t)
// landed (B(t) was issued before A(t) last iteration).
__global__ __launch_bounds__(256) void gemm_qkv(const float* __restrict__ x,
                                                const ushort* __restrict__ wT,
                                                ushort* __restrict__ Qm,
                                                ushort* __restrict__ Km,
                                                ushort* __restrict__ Vt) {
    __shared__ ushort S[20480];            // As 64x64 (4096) + Bs dbuf 2 x 128x64 (8192 each)
    ushort* As = S;
    ushort* Bs[2] = { S + 4096, S + 12288 };
    const int tid = threadIdx.x;
    const int lane = tid & 63, w = tid >> 6;
    const int row16 = lane & 15, grp = lane >> 4;
    const int wr = w >> 1, wc = w & 1;
    const int bx = blockIdx.x;             // 0..767
    const int xcd = bx & 7;
    const int i = bx >> 3;                 // 0..95
    const int by = i % 3;
    const int mt = ((xcd << 5) + i / 3) << 6;   // (xcd*32 + i/3) * 64, bijective over 0..255
    const int n0 = by * 128;

    float4v acc[2][4];
#pragma unroll
    for (int m = 0; m < 2; ++m)
#pragma unroll
        for (int n = 0; n < 4; ++n) acc[m][n] = (float4v){0.f, 0.f, 0.f, 0.f};

#define LOAD_A(KT)                                                         \
    _Pragma("unroll") for (int j = 0; j < 2; ++j) {                        \
        int idx = j * 256 + tid;                                           \
        int row = idx >> 3, slot = idx & 7;                                \
        const float* src = x + (size_t)(mt + row) * 1024 + (KT) + slot * 8;\
        va[j][0] = *(const float4*)(src);                                  \
        va[j][1] = *(const float4*)(src + 4);                              \
    }

    float4 va[2][2];
    // prologue: B(0) then A(0)  (A after B so A's reg-wait implies B landed)
    stage128x64(wT + (size_t)n0 * 1024, 1024, Bs[0], tid);
    LOAD_A(0);

    int cur = 0;
    for (int kt = 0; kt < 1024; kt += 64) {
        __builtin_amdgcn_s_barrier();      // prev compute done reading As & Bs[cur^1]
        // A: cvt prefetched regs (forces wait on A(t) => B(t) also landed) -> swizzled ds_write
#pragma unroll
        for (int j = 0; j < 2; ++j) {
            int idx = j * 256 + tid;
            int row = idx >> 3, slot = idx & 7;
            unsigned h0, h1, h2, h3;
            asm("v_cvt_pk_bf16_f32 %0, %1, %2" : "=v"(h0) : "v"(va[j][0].x), "v"(va[j][0].y));
            asm("v_cvt_pk_bf16_f32 %0, %1, %2" : "=v"(h1) : "v"(va[j][0].z), "v"(va[j][0].w));
            asm("v_cvt_pk_bf16_f32 %0, %1, %2" : "=v"(h2) : "v"(va[j][1].x), "v"(va[j][1].y));
            asm("v_cvt_pk_bf16_f32 %0, %1, %2" : "=v"(h3) : "v"(va[j][1].z), "v"(va[j][1].w));
            union { uint4v u; short8 s; } hh;
            hh.u = (uint4v){h0, h1, h2, h3};
            *(short8*)((char*)As + row * 128 + ((slot ^ (row & 7)) << 4)) = hh.s;
        }
        // prefetch next tile: B first, then A (stay in flight across compute)
        if (kt + 64 < 1024) {
            stage128x64(wT + (size_t)n0 * 1024 + kt + 64, 1024, Bs[cur ^ 1], tid);
            LOAD_A(kt + 64);
        }
        asm volatile("s_waitcnt lgkmcnt(0)" ::: "memory");   // As writes visible
        __builtin_amdgcn_s_barrier();
        compute64x128(As, Bs[cur], wr, wc, row16, grp, acc);
        cur ^= 1;
    }
#undef LOAD_A

    if (by == 2) {
        // ---- V: transpose 64t x 128d tile in LDS, write Vt[b][d][t] coalesced ----
        __builtin_amdgcn_s_barrier();      // all waves done with As/Bs before S reuse
#pragma unroll
        for (int m = 0; m < 2; ++m)
#pragma unroll
            for (int i2 = 0; i2 < 4; ++i2) {
                int trow = wr * 32 + m * 16 + grp * 4 + i2;
#pragma unroll
                for (int n = 0; n < 4; ++n) {
                    int d = wc * 64 + n * 16 + row16;
                    S[d * 72 + trow] = f2bf(acc[m][n][i2]);
                }
            }
        __syncthreads();
        const int b = mt >> 12, tloc = mt & 4095;
#pragma unroll
        for (int j = 0; j < 4; ++j) {
            int chunk = j * 256 + tid;          // 0..1023
            int d = chunk >> 3, tc = chunk & 7;
            *(short8*)(Vt + ((size_t)(b * 128 + d)) * 4096 + tloc + tc * 8) =
                *(const short8*)(S + d * 72 + tc * 8);
        }
        return;
    }

    const float oscale = (by == 0) ? (0.03125f * 1.44269504f) : 1.0f;
    ushort* dst = (by == 0) ? Qm : Km;
#pragma unroll
    for (int m = 0; m < 2; ++m)
#pragma unroll
        for (int i2 = 0; i2 < 4; ++i2) {
            int row = mt + wr * 32 + m * 16 + grp * 4 + i2;
#pragma unroll
            for (int n = 0; n < 4; ++n) {
                int coll = wc * 64 + n * 16 + row16;
                dst[(size_t)row * 128 + coll] = f2bf(acc[m][n][i2] * oscale);
            }
        }
}

// ---------------- flash attention: swapped QK^T, in-register P, KVBLK=64 ----------------
__global__ __launch_bounds__(256, 2) void attn_split(const ushort* __restrict__ Qm,
                                                     const ushort* __restrict__ Km,
                                                     const ushort* __restrict__ Vt,
                                                     ushort* __restrict__ Opart,
                                                     float* __restrict__ Lpart) {
    __shared__ ushort Ks[2][64 * 128];   // [t][d], 16 chunks/row, swz (c&8)|((c&7)^(row&7))
    __shared__ ushort Vs[2][128 * 64];   // [d][t], 8 chunks/row, swz c^(row&7)

    const int tid = threadIdx.x;
    const int lane = tid & 63, w = tid >> 6;
    const int key31 = lane & 31;                       // A-row (key) / B-row (q,d)
    const int g = lane >> 5;                           // k-group

    const int bx = blockIdx.x;
    const int xcd = bx & 7;
    const int b = xcd >> 1;
    const int combo = ((bx >> 3) << 1) | (xcd & 1);    // 0..255
    const int qb = 31 - (combo >> 3);                  // heavy blocks first
    const int s = combo & 7;

    const int ext = 2 * qb + 2;                        // 64-key tiles in block extent
    const int t0 = (s * ext) >> 3;
    const int t1 = ((s + 1) * ext) >> 3;

    const int qtile32 = qb * 4 + w;
    const int qt0 = qtile32 * 32;
    const int qmax = qt0 + 31;
    const size_t pbase = ((size_t)b * 128 + qtile32) * NSPLIT + s;
    float* mlL = Lpart + pbase * 32;

    if (t0 >= t1) {                                    // block-uniform early out
        if (lane < 32) mlL[lane] = 0.f;
        return;
    }

    const int qrow = qt0 + key31;
    // Q pre-scaled by C^-0.5*log2(e); B-operand layout: row=lane&31, k=g*8+i
    const ushort* qbp = Qm + ((size_t)(b * 4096 + qrow)) * 128 + g * 8;
    short8 qf[8];
#pragma unroll
    for (int sl = 0; sl < 8; ++sl)
        qf[sl] = *reinterpret_cast<const short8*>(qbp + sl * 16);

    f32x16 o[4];
#pragma unroll
    for (int d4 = 0; d4 < 4; ++d4)
#pragma unroll
        for (int r = 0; r < 16; ++r) o[d4][r] = 0.f;
    float lrun = 0.f;

    const ushort* kbase = Km + (size_t)b * 4096 * 128;
    const ushort* vbase = Vt + (size_t)b * 128 * 4096;

// stage one 64-key tile: K 64x16 chunks + V 128x8 chunks = 8 gload_lds/thread
#define STAGE_KV(KVT, BUF)                                                                     \
    {                                                                                          \
        const ushort* kb_ = kbase + (size_t)(KVT) * 128;                                       \
        _Pragma("unroll") for (int j = 0; j < 4; ++j) {                                        \
            int idx = j * 256 + tid;                                                           \
            int row = idx >> 4, c = idx & 15;                                                  \
            int sc_ = (c & 8) | ((c & 7) ^ (row & 7));                                         \
            __builtin_amdgcn_global_load_lds(AS1(kb_ + (size_t)row * 128 + sc_ * 8),           \
                AS3((char*)&Ks[BUF][0] + (j * 256 + (tid & 192)) * 16), 16, 0, 0);             \
        }                                                                                      \
        const ushort* vb_ = vbase + (KVT);                                                     \
        _Pragma("unroll") for (int j = 0; j < 4; ++j) {                                        \
            int idx = j * 256 + tid;                                                           \
            int row = idx >> 3, c = idx & 7;                                                   \
            int sc_ = c ^ (row & 7);                                                           \
            __builtin_amdgcn_global_load_lds(AS1(vb_ + (size_t)row * 4096 + sc_ * 8),          \
                AS3((char*)&Vs[BUF][0] + (j * 256 + (tid & 192)) * 16), 16, 0, 0);             \
        }                                                                                      \
    }

    STAGE_KV(t0 * 64, 0);

    int cur = 0;
    for (int t = t0; t < t1; ++t) {
        const int kvt = t * 64;
        __builtin_amdgcn_s_barrier();                  // prev compute done reading cur^1
        if (t + 1 < t1) {
            STAGE_KV((t + 1) * 64, cur ^ 1);
            asm volatile("s_waitcnt vmcnt(8)" ::: "memory");  // tile t's 8 landed; t+1 in flight
        } else {
            asm volatile("s_waitcnt vmcnt(0)" ::: "memory");
        }
        __builtin_amdgcn_s_barrier();                  // buf cur readable by all waves

        if (kvt <= qmax) {
            // ---- swapped QK^T: two 32x32 outputs (keys 0..31, 32..63) ----
            const char* Kb = (const char*)&Ks[cur][0];
            f32x16 st0, st1;
#pragma unroll
            for (int r = 0; r < 16; ++r) { st0[r] = 0.f; st1[r] = 0.f; }
#pragma unroll
            for (int sl = 0; sl < 8; ++sl) {
                int c = sl * 2 + g;
                int sc_ = (c & 8) | ((c & 7) ^ (key31 & 7));
                short8 k0 = *(const short8*)(Kb + key31 * 256 + sc_ * 16);
                st0 = __builtin_amdgcn_mfma_f32_32x32x16_bf16(k0, qf[sl], st0, 0, 0, 0);
                short8 k1 = *(const short8*)(Kb + (32 + key31) * 256 + sc_ * 16);
                st1 = __builtin_amdgcn_mfma_f32_32x32x16_bf16(k1, qf[sl], st1, 0, 0, 0);
            }
            // ---- causal mask ----
            if (kvt + 63 > qt0) {
#pragma unroll
                for (int r = 0; r < 16; ++r) {
                    int key = kvt + (r & 3) + 8 * (r >> 2) + 4 * g;
                    if (key > qrow) st0[r] = -3e38f;
                    if (key + 32 > qrow) st1[r] = -3e38f;
                }
            }
            // ---- static-max softmax in-register ----
#pragma unroll
            for (int r = 0; r < 16; ++r) {
                float p0 = exp2f(st0[r]);
                float p1 = exp2f(st1[r]);
                st0[r] = p0; st1[r] = p1;
                lrun += p0 + p1;
            }
            // ---- PA fragments: 16 cvt_pk + 8 permlane32_swap (T12) ----
            unsigned pk0, pk1, pk2, pk3, pk4, pk5, pk6, pk7;
            unsigned qk0, qk1, qk2, qk3, qk4, qk5, qk6, qk7;
            asm("v_cvt_pk_bf16_f32 %0, %1, %2" : "=v"(pk0) : "v"(st0[0]),  "v"(st0[1]));
            asm("v_cvt_pk_bf16_f32 %0, %1, %2" : "=v"(pk1) : "v"(st0[2]),  "v"(st0[3]));
            asm("v_cvt_pk_bf16_f32 %0, %1, %2" : "=v"(pk2) : "v"(st0[4]),  "v"(st0[5]));
            asm("v_cvt_pk_bf16_f32 %0, %1, %2" : "=v"(pk3) : "v"(st0[6]),  "v"(st0[7]));
            asm("v_cvt_pk_bf16_f32 %0, %1, %2" : "=v"(pk4) : "v"(st0[8]),  "v"(st0[9]));
            asm("v_cvt_pk_bf16_f32 %0, %1, %2" : "=v"(pk5) : "v"(st0[10]), "v"(st0[11]));
            asm("v_cvt_pk_bf16_f32 %0, %1, %2" : "=v"(pk6) : "v"(st0[12]), "v"(st0[13]));
            asm("v_cvt_pk_bf16_f32 %0, %1, %2" : "=v"(pk7) : "v"(st0[14]), "v"(st0[15]));
            asm("v_cvt_pk_bf16_f32 %0, %1, %2" : "=v"(qk0) : "v"(st1[0]),  "v"(st1[1]));
            asm("v_cvt_pk_bf16_f32 %0, %1, %2" : "=v"(qk1) : "v"(st1[2]),  "v"(st1[3]));
            asm("v_cvt_pk_bf16_f32 %0, %1, %2" : "=v"(qk2) : "v"(st1[4]),  "v"(st1[5]));
            asm("v_cvt_pk_bf16_f32 %0, %1, %2" : "=v"(qk3) : "v"(st1[6]),  "v"(st1[7]));
            asm("v_cvt_pk_bf16_f32 %0, %1, %2" : "=v"(qk4) : "v"(st1[8]),  "v"(st1[9]));
            asm("v_cvt_pk_bf16_f32 %0, %1, %2" : "=v"(qk5) : "v"(st1[10]), "v"(st1[11]));
            asm("v_cvt_pk_bf16_f32 %0, %1, %2" : "=v"(qk6) : "v"(st1[12]), "v"(st1[13]));
            asm("v_cvt_pk_bf16_f32 %0, %1, %2" : "=v"(qk7) : "v"(st1[14]), "v"(st1[15]));
            asm volatile("v_permlane32_swap_b32 %0, %1" : "+v"(pk0), "+v"(pk2));
            asm volatile("v_permlane32_swap_b32 %0, %1" : "+v"(pk1), "+v"(pk3));
            asm volatile("v_permlane32_swap_b32 %0, %1" : "+v"(pk4), "+v"(pk6));
            asm volatile("v_permlane32_swap_b32 %0, %1" : "+v"(pk5), "+v"(pk7));
            asm volatile("v_permlane32_swap_b32 %0, %1" : "+v"(qk0), "+v"(qk2));
            asm volatile("v_permlane32_swap_b32 %0, %1" : "+v"(qk1), "+v"(qk3));
            asm volatile("v_permlane32_swap_b32 %0, %1" : "+v"(qk4), "+v"(qk6));
            asm volatile("v_permlane32_swap_b32 %0, %1" : "+v"(qk5), "+v"(qk7));
            union FW { uint4v u; short8 s; };
            FW f0; f0.u = (uint4v){pk0, pk1, pk2, pk3};
            FW f1; f1.u = (uint4v){pk4, pk5, pk6, pk7};
            FW f2; f2.u = (uint4v){qk0, qk1, qk2, qk3};
            FW f3; f3.u = (uint4v){qk4, qk5, qk6, qk7};
            short8 fa0 = f0.s;                         // keys kvt+0..15
            short8 fa1 = f1.s;                         // keys kvt+16..31
            short8 fa2 = f2.s;                         // keys kvt+32..47
            short8 fa3 = f3.s;                         // keys kvt+48..63
            // ---- PV: O[q][d] += P x V over 64 keys (4 k-slots) ----
            const char* Vb = (const char*)&Vs[cur][0];
#pragma unroll
            for (int d4 = 0; d4 < 4; ++d4) {
                int d = d4 * 32 + key31;
                int sw = d & 7;
                short8 v0 = *(const short8*)(Vb + d * 128 + ((0 * 2 + g) ^ sw) * 16);
                o[d4] = __builtin_amdgcn_mfma_f32_32x32x16_bf16(fa0, v0, o[d4], 0, 0, 0);
                short8 v1 = *(const short8*)(Vb + d * 128 + ((1 * 2 + g) ^ sw) * 16);
                o[d4] = __builtin_amdgcn_mfma_f32_32x32x16_bf16(fa1, v1, o[d4], 0, 0, 0);
                short8 v2 = *(const short8*)(Vb + d * 128 + ((2 * 2 + g) ^ sw) * 16);
                o[d4] = __builtin_amdgcn_mfma_f32_32x32x16_bf16(fa2, v2, o[d4], 0, 0, 0);
                short8 v3 = *(const short8*)(Vb + d * 128 + ((3 * 2 + g) ^ sw) * 16);
                o[d4] = __builtin_amdgcn_mfma_f32_32x32x16_bf16(fa3, v3, o[d4], 0, 0, 0);
            }
        }
        cur ^= 1;
    }
#undef STAGE_KV

    // ---- merge the two k-halves' row sums ----
    lrun += __shfl_xor(lrun, 32);
    // ---- write partial (unnormalized O bf16, denom l) ----
    // o layout: row q = (r&3)+8*(r>>2)+4g, col d = d4*32+key31
    ushort* ob = Opart + pbase * 32 * 128;
#pragma unroll
    for (int d4 = 0; d4 < 4; ++d4)
#pragma unroll
        for (int r = 0; r < 16; ++r) {
            int qr = (r & 3) + 8 * (r >> 2) + 4 * g;
            ob[(size_t)qr * 128 + d4 * 32 + key31] = f2bf(o[d4][r]);
        }
    if (lane < 32) mlL[lane] = lrun;
}

// ---------------- combine: plain sum over splits (static max), 2 rows/block ----------------
__global__ __launch_bounds__(256) void attn_combine(const ushort* __restrict__ Opart,
                                                    const float* __restrict__ Lpart,
                                                    ushort* __restrict__ AO) {
    const int row = blockIdx.x * 2 + (threadIdx.x >> 7);
    const int b = row >> 12, t = row & 4095;
    const int qtile = t >> 5, r = t & 31;
    const size_t sb = (((size_t)b * 128 + qtile) * NSPLIT);
    const int col = threadIdx.x & 127;
    float acc = 0.f, denom = 0.f;
#pragma unroll
    for (int s = 0; s < NSPLIT; ++s) {
        float l = Lpart[(sb + s) * 32 + r];
        if (l > 0.f) {
            denom += l;
            acc += bf2f(Opart[((sb + s) * 32 + r) * 128 + col]);
        }
    }
    AO[(size_t)row * 128 + col] = f2bf(acc / denom);
}

// ---------------- GEMM2: out = AO @ w_out + b_out, BM=64 ----------------
__global__ __launch_bounds__(256) void gemm_out(const ushort* __restrict__ AO,
                                                const ushort* __restrict__ wT,
                                                const float* __restrict__ bias,
                                                float* __restrict__ out) {
    __shared__ ushort As[64 * 64];
    __shared__ ushort Bs[128 * 64];
    const int tid = threadIdx.x;
    const int lane = tid & 63, w = tid >> 6;
    const int row16 = lane & 15, grp = lane >> 4;
    const int wr = w >> 1, wc = w & 1;
    const int mt = blockIdx.x * 64;
    const int n0 = blockIdx.y * 128;

    float4v acc[2][4];
#pragma unroll
    for (int m = 0; m < 2; ++m)
#pragma unroll
        for (int n = 0; n < 4; ++n) acc[m][n] = (float4v){0.f, 0.f, 0.f, 0.f};

#pragma unroll
    for (int kt = 0; kt < 128; kt += 64) {
        stage64x64(AO + (size_t)mt * 128 + kt, 128, As, tid);
        stage128x64(wT + (size_t)n0 * 128 + kt, 128, Bs, tid);
        __syncthreads();
        compute64x128(As, Bs, wr, wc, row16, grp, acc);
        __syncthreads();
    }

#pragma unroll
    for (int n = 0; n < 4; ++n) {
        int col = n0 + wc * 64 + n * 16 + row16;
        float bv = bias[col];
#pragma unroll
        for (int m = 0; m < 2; ++m)
#pragma unroll
            for (int i = 0; i < 4; ++i) {
                int row = mt + wr * 32 + m * 16 + grp * 4 + i;
                out[(size_t)row * 1024 + col] = acc[m][n][i] + bv;
            }
    }
}

extern "C" void kernel_launch(void* const* d_in, const int* in_sizes, int n_in,
                              void* d_out, int out_size, void* d_ws, size_t ws_size,
                              hipStream_t stream) {
    const float* x     = (const float*)d_in[0];   // [4,4096,1024]
    const float* w_qkv = (const float*)d_in[1];   // [1024,384]
    const float* w_out = (const float*)d_in[2];   // [128,1024]
    const float* b_out = (const float*)d_in[3];   // [1024]
    float* out = (float*)d_out;

    char* ws = (char*)d_ws;
    ushort* wqkvT = (ushort*)(ws + 33554432);      //    786,432 B
    ushort* woutT = (ushort*)(ws + 34340864);      //    262,144 B
    ushort* Qm    = (ushort*)(ws + 34603008);      //  4,194,304 B
    ushort* Km    = (ushort*)(ws + 38797312);      //  4,194,304 B
    ushort* Vt    = (ushort*)(ws + 42991616);      //  4,194,304 B
    ushort* AO    = (ushort*)(ws + 47185920);      //  4,194,304 B
    ushort* Opart = (ushort*)(ws);                 // 33,554,432 B (ws base)
    float* Lpart  = (float*)(ws + 51380224);       //    524,288 B

    // both weight transposes in one launch
    transpose_cast2<<<dim3(2048), dim3(256), 0, stream>>>(w_qkv, wqkvT, w_out, woutT);

    // QKV projection: fused cast, BM=64, XCD-localized mapping, dbuf B
    gemm_qkv<<<dim3(768), dim3(256), 0, stream>>>(x, wqkvT, Qm, Km, Vt);

    // causal flash attention: swapped QK^T, in-register P, KVBLK=64, NSPLIT=8
    attn_split<<<dim3(1024), dim3(256), 0, stream>>>(Qm, Km, Vt, Opart, Lpart);
    attn_combine<<<dim3(8192), dim3(256), 0, stream>>>(Opart, Lpart, AO);

    // output projection + bias (tiled, BM=64)
    gemm_out<<<dim3(256, 8), dim3(256), 0, stream>>>(AO, woutT, b_out, out);
}